// Round 1
// baseline (1161.336 us; speedup 1.0000x reference)
//
#include <hip/hip_runtime.h>
#include <hip/hip_bf16.h>

// Problem constants (fixed by the reference)
#define NN 50000
#define NE 800000
#define NG 64
#define IND 128
#define HID 128
#define OUTD 768

// ---------------------------------------------------------------------------
// init: deg=1, hist=0, pool sums/cnt=0, wmax=0
__global__ void init_kernel(float* deg, int* hist, float* sums, float* cnt,
                            unsigned int* wmax, int n) {
    int i = blockIdx.x * blockDim.x + threadIdx.x;
    if (i < n) { deg[i] = 1.0f; hist[i] = 0; }
    if (i < NG * 32) sums[i] = 0.0f;
    if (i < NG) cnt[i] = 0.0f;
    if (i == 0) *wmax = 0u;
}

// max(edge_attr) via block reduce + uint atomicMax (valid: all values > 0)
__global__ void max_kernel(const float* __restrict__ ea, unsigned int* wmax, int nE) {
    __shared__ float red[256];
    float m = 0.0f;
    for (int i = blockIdx.x * blockDim.x + threadIdx.x; i < nE;
         i += gridDim.x * blockDim.x)
        m = fmaxf(m, ea[i]);
    red[threadIdx.x] = m;
    __syncthreads();
    for (int off = 128; off > 0; off >>= 1) {
        if (threadIdx.x < off)
            red[threadIdx.x] = fmaxf(red[threadIdx.x], red[threadIdx.x + off]);
        __syncthreads();
    }
    if (threadIdx.x == 0) atomicMax(wmax, __float_as_uint(red[0]));
}

// deg[dst] += w ; hist[dst] += 1
__global__ void deg_hist_kernel(const int* __restrict__ dst, const float* __restrict__ ea,
                                const unsigned int* __restrict__ wmax,
                                float* deg, int* hist, int nE) {
    int e = blockIdx.x * blockDim.x + threadIdx.x;
    if (e >= nE) return;
    float rw = 1.0f / __uint_as_float(*wmax);
    int d = dst[e];
    atomicAdd(&deg[d], ea[e] * rw);
    atomicAdd(&hist[d], 1);
}

__global__ void dinv_kernel(const float* __restrict__ deg, float* dinv, float* invdeg, int n) {
    int i = blockIdx.x * blockDim.x + threadIdx.x;
    if (i >= n) return;
    float d = deg[i];
    dinv[i] = rsqrtf(d);
    invdeg[i] = 1.0f / d;
}

// exclusive scan of hist -> rowptr (and a second copy in cursor), single block
__global__ __launch_bounds__(1024) void scan_kernel(const int* __restrict__ hist,
                                                    int* __restrict__ rowptr,
                                                    int* __restrict__ cursor, int n) {
    __shared__ int part[1024];
    const int tid = threadIdx.x;
    const int chunk = (n + 1023) >> 10;
    const int lo = tid * chunk;
    const int hi = min(lo + chunk, n);
    int s = 0;
    for (int i = lo; i < hi; ++i) s += hist[i];
    part[tid] = s;
    __syncthreads();
    for (int off = 1; off < 1024; off <<= 1) {
        int v = (tid >= off) ? part[tid - off] : 0;
        __syncthreads();
        part[tid] += v;
        __syncthreads();
    }
    int run = (tid == 0) ? 0 : part[tid - 1];
    for (int i = lo; i < hi; ++i) {
        rowptr[i] = run;
        cursor[i] = run;
        run += hist[i];
    }
    if (tid == 1023) rowptr[n] = part[1023];
}

// bucket edges by dst; store src and the layer-invariant coefficient
__global__ void scatter_kernel(const int* __restrict__ src, const int* __restrict__ dst,
                               const float* __restrict__ ea,
                               const unsigned int* __restrict__ wmax,
                               const float* __restrict__ dinv,
                               int* cursor, int* esrc, float* ecoef, int nE) {
    int e = blockIdx.x * blockDim.x + threadIdx.x;
    if (e >= nE) return;
    float rw = 1.0f / __uint_as_float(*wmax);
    int s = src[e], d = dst[e];
    int pos = atomicAdd(&cursor[d], 1);
    esrc[pos] = s;
    ecoef[pos] = dinv[s] * (ea[e] * rw) * dinv[d];
}

// ---------------------------------------------------------------------------
// GEMM: Y[N,D-slice] = X[N,K] @ W[K,D], fp32 vector ALU, LDS tiled,
// 4 rows x 4 cols per thread. X tile stored k-grouped as float4 (aligned b128).
template <int K, int D, int DT>
__global__ __launch_bounds__(256) void gemm_kernel(const float* __restrict__ X,
                                                   const float* __restrict__ W,
                                                   float* __restrict__ Y, int nRows) {
    constexpr int CG = DT / 4;       // col groups
    constexpr int RT = 1024 / CG;    // rows per block
    constexpr int KG = K / 4;        // k groups
    constexpr int XS = RT + 1;       // XsT4 row stride (float4 units) — breaks bank clash
    __shared__ float4 XsT4[KG * XS];
    __shared__ float Ws[K * DT];

    const int tid = threadIdx.x;
    const int rowbase = blockIdx.x * RT;
    const int cbase = blockIdx.y * DT;

    for (int q = tid; q < K * DT / 4; q += 256) {
        int kw = q / CG;
        int c0 = (q - kw * CG) * 4;
        *(float4*)&Ws[kw * DT + c0] = *(const float4*)&W[kw * D + cbase + c0];
    }
    for (int q = tid; q < RT * KG; q += 256) {
        int r = q / KG;
        int kg = q - r * KG;
        int grow = rowbase + r;
        float4 xv = make_float4(0.f, 0.f, 0.f, 0.f);
        if (grow < nRows) xv = *(const float4*)&X[(size_t)grow * K + kg * 4];
        XsT4[kg * XS + r] = xv;
    }
    __syncthreads();

    const int c0 = (tid % CG) * 4;
    const int r0 = (tid / CG) * 4;
    float acc[4][4] = {};
#pragma unroll 4
    for (int kg = 0; kg < KG; ++kg) {
        float4 xr[4], wk[4];
#pragma unroll
        for (int i = 0; i < 4; ++i) xr[i] = XsT4[kg * XS + r0 + i];
#pragma unroll
        for (int m = 0; m < 4; ++m) wk[m] = *(const float4*)&Ws[(kg * 4 + m) * DT + c0];
#pragma unroll
        for (int i = 0; i < 4; ++i) {
            float xi[4] = {xr[i].x, xr[i].y, xr[i].z, xr[i].w};
#pragma unroll
            for (int m = 0; m < 4; ++m) {
                acc[i][0] = fmaf(xi[m], wk[m].x, acc[i][0]);
                acc[i][1] = fmaf(xi[m], wk[m].y, acc[i][1]);
                acc[i][2] = fmaf(xi[m], wk[m].z, acc[i][2]);
                acc[i][3] = fmaf(xi[m], wk[m].w, acc[i][3]);
            }
        }
    }
#pragma unroll
    for (int i = 0; i < 4; ++i) {
        int grow = rowbase + r0 + i;
        if (grow < nRows)
            *(float4*)&Y[(size_t)grow * D + cbase + c0] =
                make_float4(acc[i][0], acc[i][1], acc[i][2], acc[i][3]);
    }
}

// ---------------------------------------------------------------------------
// Aggregation: out[n] = relu( sum_in coef*H[src] + invdeg[n]*H[n] + b )
// D=128: 1 node/wave, float2/lane.  D=64: 1 node/wave, float/lane.
// D=32: 2 nodes/wave (half-wave each).
template <int D>
__global__ __launch_bounds__(256) void agg_kernel(const float* __restrict__ H,
                                                  const int* __restrict__ rowptr,
                                                  const int* __restrict__ esrc,
                                                  const float* __restrict__ ecoef,
                                                  const float* __restrict__ invdeg,
                                                  const float* __restrict__ bias,
                                                  float* __restrict__ out, int nNodes) {
    const int lane = threadIdx.x & 63;
    const int wid = (blockIdx.x << 2) | (threadIdx.x >> 6);
    if constexpr (D >= 64) {
        const int n = __builtin_amdgcn_readfirstlane(wid);
        if (n >= nNodes) return;
        constexpr int V = D / 64;  // 2 or 1
        const int f = lane * V;
        const int s0 = rowptr[n], s1 = rowptr[n + 1];
        if constexpr (V == 2) {
            float a0 = 0.f, a1 = 0.f;
            for (int e = s0; e < s1; ++e) {
                const int s = esrc[e];
                const float c = ecoef[e];
                float2 h = *(const float2*)(H + (size_t)s * D + f);
                a0 = fmaf(c, h.x, a0);
                a1 = fmaf(c, h.y, a1);
            }
            const float id = invdeg[n];
            float2 hn = *(const float2*)(H + (size_t)n * D + f);
            float2 bv = *(const float2*)(bias + f);
            a0 = fmaxf(fmaf(id, hn.x, a0) + bv.x, 0.f);
            a1 = fmaxf(fmaf(id, hn.y, a1) + bv.y, 0.f);
            *(float2*)(out + (size_t)n * D + f) = make_float2(a0, a1);
        } else {
            float a0 = 0.f;
            for (int e = s0; e < s1; ++e)
                a0 = fmaf(ecoef[e], H[(size_t)esrc[e] * D + f], a0);
            a0 = fmaxf(fmaf(invdeg[n], H[(size_t)n * D + f], a0) + bias[f], 0.f);
            out[(size_t)n * D + f] = a0;
        }
    } else {  // D == 32
        const int sub = lane >> 5;
        const int f = lane & 31;
        const int n = wid * 2 + sub;
        if (n >= nNodes) return;
        float a0 = 0.f;
        const int s0 = rowptr[n], s1 = rowptr[n + 1];
        for (int e = s0; e < s1; ++e)
            a0 = fmaf(ecoef[e], H[(size_t)esrc[e] * D + f], a0);
        a0 = fmaxf(fmaf(invdeg[n], H[(size_t)n * D + f], a0) + bias[f], 0.f);
        out[(size_t)n * D + f] = a0;
    }
}

// ---------------------------------------------------------------------------
__global__ void pool_kernel(const float* __restrict__ h, const int* __restrict__ batch,
                            float* sums, float* cnt, int n) {
    int i = blockIdx.x * blockDim.x + threadIdx.x;
    if (i >= n) return;
    int g = batch[i];
    atomicAdd(&cnt[g], 1.0f);
    const float* hp = h + (size_t)i * 32;
    float* sp = sums + g * 32;
#pragma unroll
    for (int d = 0; d < 32; ++d) atomicAdd(&sp[d], hp[d]);
}

__global__ void final_kernel(const float* __restrict__ sums, const float* __restrict__ cnt,
                             const float* __restrict__ Wl, const float* __restrict__ bl,
                             float* __restrict__ out) {
    int idx = blockIdx.x * blockDim.x + threadIdx.x;  // [0, 64*768)
    int g = idx / OUTD, o = idx - g * OUTD;
    float inv = 1.0f / fmaxf(cnt[g], 1.0f);
    float acc = bl[o];
#pragma unroll
    for (int k = 0; k < 32; ++k)
        acc = fmaf(sums[g * 32 + k] * inv, Wl[k * OUTD + o], acc);
    out[idx] = acc;
}

// ---------------------------------------------------------------------------
extern "C" void kernel_launch(void* const* d_in, const int* in_sizes, int n_in,
                              void* d_out, int out_size, void* d_ws, size_t ws_size,
                              hipStream_t stream) {
    const float* x = (const float*)d_in[0];
    const int* eidx = (const int*)d_in[1];
    const float* ea = (const float*)d_in[2];
    const int* batch = (const int*)d_in[3];
    const float* W1 = (const float*)d_in[4];
    const float* b1 = (const float*)d_in[5];
    const float* W2 = (const float*)d_in[6];
    const float* b2 = (const float*)d_in[7];
    const float* W3 = (const float*)d_in[8];
    const float* b3 = (const float*)d_in[9];
    const float* Wl = (const float*)d_in[10];
    const float* bl = (const float*)d_in[11];
    const int* src = eidx;
    const int* dst = eidx + NE;

    char* p = (char*)d_ws;
    auto take = [&](size_t bytes) {
        char* r = p;
        p += (bytes + 255) & ~(size_t)255;
        return r;
    };
    float* deg = (float*)take(NN * 4);
    float* dinv = (float*)take(NN * 4);
    float* invdeg = (float*)take(NN * 4);
    int* hist = (int*)take(NN * 4);
    int* rowptr = (int*)take((NN + 1) * 4);
    int* cursor = (int*)take(NN * 4);
    int* esrc = (int*)take((size_t)NE * 4);
    float* ecoef = (float*)take((size_t)NE * 4);
    float* sums = (float*)take(NG * 32 * 4);
    float* cnt = (float*)take(NG * 4);
    unsigned int* wmax = (unsigned int*)take(4);
    float* bufA = (float*)take((size_t)NN * 128 * 4);
    float* bufB = (float*)take((size_t)NN * 128 * 4);

    const int nblk = (NN + 255) / 256;   // 196
    const int eblk = (NE + 255) / 256;   // 3125

    init_kernel<<<nblk, 256, 0, stream>>>(deg, hist, sums, cnt, wmax, NN);
    max_kernel<<<128, 256, 0, stream>>>(ea, wmax, NE);
    deg_hist_kernel<<<eblk, 256, 0, stream>>>(dst, ea, wmax, deg, hist, NE);
    dinv_kernel<<<nblk, 256, 0, stream>>>(deg, dinv, invdeg, NN);
    scan_kernel<<<1, 1024, 0, stream>>>(hist, rowptr, cursor, NN);
    scatter_kernel<<<eblk, 256, 0, stream>>>(src, dst, ea, wmax, dinv, cursor, esrc, ecoef, NE);

    // layer 1: H = x @ W1 (128->128), then aggregate+relu
    gemm_kernel<128, 128, 64><<<dim3((NN + 63) / 64, 2), 256, 0, stream>>>(x, W1, bufA, NN);
    agg_kernel<128><<<(NN + 3) / 4, 256, 0, stream>>>(bufA, rowptr, esrc, ecoef, invdeg, b1, bufB, NN);
    // layer 2: 128->64
    gemm_kernel<128, 64, 64><<<dim3((NN + 63) / 64, 1), 256, 0, stream>>>(bufB, W2, bufA, NN);
    agg_kernel<64><<<(NN + 3) / 4, 256, 0, stream>>>(bufA, rowptr, esrc, ecoef, invdeg, b2, bufB, NN);
    // layer 3: 64->32
    gemm_kernel<64, 32, 32><<<dim3((NN + 127) / 128, 1), 256, 0, stream>>>(bufB, W3, bufA, NN);
    agg_kernel<32><<<(NN + 7) / 8, 256, 0, stream>>>(bufA, rowptr, esrc, ecoef, invdeg, b3, bufB, NN);

    pool_kernel<<<nblk, 256, 0, stream>>>(bufB, batch, sums, cnt, NN);
    final_kernel<<<(NG * OUTD) / 256, 256, 0, stream>>>(sums, cnt, Wl, bl, (float*)d_out);
}

// Round 2
// 588.886 us; speedup vs baseline: 1.9721x; 1.9721x over previous
//
#include <hip/hip_runtime.h>
#include <hip/hip_bf16.h>

// Problem constants (fixed by the reference)
#define NN 50000
#define NE 800000
#define NG 64
#define IND 128
#define HID 128
#define OUTD 768

// ---------------------------------------------------------------------------
// init: deg=1, hist=0, wmax=0
__global__ void init_kernel(float* deg, int* hist, unsigned int* wmax, int n) {
    int i = blockIdx.x * blockDim.x + threadIdx.x;
    if (i < n) { deg[i] = 1.0f; hist[i] = 0; }
    if (i == 0) *wmax = 0u;
}

// max(edge_attr) via block reduce + uint atomicMax (valid: all values > 0)
__global__ void max_kernel(const float* __restrict__ ea, unsigned int* wmax, int nE) {
    __shared__ float red[256];
    float m = 0.0f;
    for (int i = blockIdx.x * blockDim.x + threadIdx.x; i < nE;
         i += gridDim.x * blockDim.x)
        m = fmaxf(m, ea[i]);
    red[threadIdx.x] = m;
    __syncthreads();
    for (int off = 128; off > 0; off >>= 1) {
        if (threadIdx.x < off)
            red[threadIdx.x] = fmaxf(red[threadIdx.x], red[threadIdx.x + off]);
        __syncthreads();
    }
    if (threadIdx.x == 0) atomicMax(wmax, __float_as_uint(red[0]));
}

// deg[dst] += w ; hist[dst] += 1
__global__ void deg_hist_kernel(const int* __restrict__ dst, const float* __restrict__ ea,
                                const unsigned int* __restrict__ wmax,
                                float* deg, int* hist, int nE) {
    int e = blockIdx.x * blockDim.x + threadIdx.x;
    if (e >= nE) return;
    float rw = 1.0f / __uint_as_float(*wmax);
    int d = dst[e];
    atomicAdd(&deg[d], ea[e] * rw);
    atomicAdd(&hist[d], 1);
}

__global__ void dinv_kernel(const float* __restrict__ deg, float* dinv, float* invdeg, int n) {
    int i = blockIdx.x * blockDim.x + threadIdx.x;
    if (i >= n) return;
    float d = deg[i];
    dinv[i] = rsqrtf(d);
    invdeg[i] = 1.0f / d;
}

// exclusive scan of hist -> rowptr (and a second copy in cursor), single block
__global__ __launch_bounds__(1024) void scan_kernel(const int* __restrict__ hist,
                                                    int* __restrict__ rowptr,
                                                    int* __restrict__ cursor, int n) {
    __shared__ int part[1024];
    const int tid = threadIdx.x;
    const int chunk = (n + 1023) >> 10;
    const int lo = tid * chunk;
    const int hi = min(lo + chunk, n);
    int s = 0;
    for (int i = lo; i < hi; ++i) s += hist[i];
    part[tid] = s;
    __syncthreads();
    for (int off = 1; off < 1024; off <<= 1) {
        int v = (tid >= off) ? part[tid - off] : 0;
        __syncthreads();
        part[tid] += v;
        __syncthreads();
    }
    int run = (tid == 0) ? 0 : part[tid - 1];
    for (int i = lo; i < hi; ++i) {
        rowptr[i] = run;
        cursor[i] = run;
        run += hist[i];
    }
    if (tid == 1023) rowptr[n] = part[1023];
}

// bucket edges by dst; store src and the layer-invariant coefficient
__global__ void scatter_kernel(const int* __restrict__ src, const int* __restrict__ dst,
                               const float* __restrict__ ea,
                               const unsigned int* __restrict__ wmax,
                               const float* __restrict__ dinv,
                               int* cursor, int* esrc, float* ecoef, int nE) {
    int e = blockIdx.x * blockDim.x + threadIdx.x;
    if (e >= nE) return;
    float rw = 1.0f / __uint_as_float(*wmax);
    int s = src[e], d = dst[e];
    int pos = atomicAdd(&cursor[d], 1);
    esrc[pos] = s;
    ecoef[pos] = dinv[s] * (ea[e] * rw) * dinv[d];
}

// ---------------------------------------------------------------------------
// GEMM: Y[N,D-slice] = X[N,K] @ W[K,D], fp32 vector ALU, LDS tiled,
// 4 rows x 4 cols per thread. X tile stored k-grouped as float4 (aligned b128).
template <int K, int D, int DT>
__global__ __launch_bounds__(256) void gemm_kernel(const float* __restrict__ X,
                                                   const float* __restrict__ W,
                                                   float* __restrict__ Y, int nRows) {
    constexpr int CG = DT / 4;       // col groups
    constexpr int RT = 1024 / CG;    // rows per block
    constexpr int KG = K / 4;        // k groups
    constexpr int XS = RT + 1;       // XsT4 row stride (float4 units) — breaks bank clash
    __shared__ float4 XsT4[KG * XS];
    __shared__ float Ws[K * DT];

    const int tid = threadIdx.x;
    const int rowbase = blockIdx.x * RT;
    const int cbase = blockIdx.y * DT;

    for (int q = tid; q < K * DT / 4; q += 256) {
        int kw = q / CG;
        int c0 = (q - kw * CG) * 4;
        *(float4*)&Ws[kw * DT + c0] = *(const float4*)&W[kw * D + cbase + c0];
    }
    for (int q = tid; q < RT * KG; q += 256) {
        int r = q / KG;
        int kg = q - r * KG;
        int grow = rowbase + r;
        float4 xv = make_float4(0.f, 0.f, 0.f, 0.f);
        if (grow < nRows) xv = *(const float4*)&X[(size_t)grow * K + kg * 4];
        XsT4[kg * XS + r] = xv;
    }
    __syncthreads();

    const int c0 = (tid % CG) * 4;
    const int r0 = (tid / CG) * 4;
    float acc[4][4] = {};
#pragma unroll 4
    for (int kg = 0; kg < KG; ++kg) {
        float4 xr[4], wk[4];
#pragma unroll
        for (int i = 0; i < 4; ++i) xr[i] = XsT4[kg * XS + r0 + i];
#pragma unroll
        for (int m = 0; m < 4; ++m) wk[m] = *(const float4*)&Ws[(kg * 4 + m) * DT + c0];
#pragma unroll
        for (int i = 0; i < 4; ++i) {
            float xi[4] = {xr[i].x, xr[i].y, xr[i].z, xr[i].w};
#pragma unroll
            for (int m = 0; m < 4; ++m) {
                acc[i][0] = fmaf(xi[m], wk[m].x, acc[i][0]);
                acc[i][1] = fmaf(xi[m], wk[m].y, acc[i][1]);
                acc[i][2] = fmaf(xi[m], wk[m].z, acc[i][2]);
                acc[i][3] = fmaf(xi[m], wk[m].w, acc[i][3]);
            }
        }
    }
#pragma unroll
    for (int i = 0; i < 4; ++i) {
        int grow = rowbase + r0 + i;
        if (grow < nRows)
            *(float4*)&Y[(size_t)grow * D + cbase + c0] =
                make_float4(acc[i][0], acc[i][1], acc[i][2], acc[i][3]);
    }
}

// ---------------------------------------------------------------------------
// Aggregation: out[n] = relu( sum_in coef*H[src] + invdeg[n]*H[n] + b )
template <int D>
__global__ __launch_bounds__(256) void agg_kernel(const float* __restrict__ H,
                                                  const int* __restrict__ rowptr,
                                                  const int* __restrict__ esrc,
                                                  const float* __restrict__ ecoef,
                                                  const float* __restrict__ invdeg,
                                                  const float* __restrict__ bias,
                                                  float* __restrict__ out, int nNodes) {
    const int lane = threadIdx.x & 63;
    const int wid = (blockIdx.x << 2) | (threadIdx.x >> 6);
    if constexpr (D >= 64) {
        const int n = __builtin_amdgcn_readfirstlane(wid);
        if (n >= nNodes) return;
        constexpr int V = D / 64;  // 2 or 1
        const int f = lane * V;
        const int s0 = rowptr[n], s1 = rowptr[n + 1];
        if constexpr (V == 2) {
            float a0 = 0.f, a1 = 0.f;
            for (int e = s0; e < s1; ++e) {
                const int s = esrc[e];
                const float c = ecoef[e];
                float2 h = *(const float2*)(H + (size_t)s * D + f);
                a0 = fmaf(c, h.x, a0);
                a1 = fmaf(c, h.y, a1);
            }
            const float id = invdeg[n];
            float2 hn = *(const float2*)(H + (size_t)n * D + f);
            float2 bv = *(const float2*)(bias + f);
            a0 = fmaxf(fmaf(id, hn.x, a0) + bv.x, 0.f);
            a1 = fmaxf(fmaf(id, hn.y, a1) + bv.y, 0.f);
            *(float2*)(out + (size_t)n * D + f) = make_float2(a0, a1);
        } else {
            float a0 = 0.f;
            for (int e = s0; e < s1; ++e)
                a0 = fmaf(ecoef[e], H[(size_t)esrc[e] * D + f], a0);
            a0 = fmaxf(fmaf(invdeg[n], H[(size_t)n * D + f], a0) + bias[f], 0.f);
            out[(size_t)n * D + f] = a0;
        }
    } else {  // D == 32
        const int sub = lane >> 5;
        const int f = lane & 31;
        const int n = wid * 2 + sub;
        if (n >= nNodes) return;
        float a0 = 0.f;
        const int s0 = rowptr[n], s1 = rowptr[n + 1];
        for (int e = s0; e < s1; ++e)
            a0 = fmaf(ecoef[e], H[(size_t)esrc[e] * D + f], a0);
        a0 = fmaxf(fmaf(invdeg[n], H[(size_t)n * D + f], a0) + bias[f], 0.f);
        out[(size_t)n * D + f] = a0;
    }
}

// ---------------------------------------------------------------------------
// Pool: batch is SORTED -> one block per graph, binary search the node range,
// strided coalesced sum, LDS reduce, write pooled[g][f] = sum / max(cnt,1).
// Zero atomics, deterministic.
__global__ __launch_bounds__(256) void pool2_kernel(const float* __restrict__ h,
                                                    const int* __restrict__ batch,
                                                    float* __restrict__ pooled, int n) {
    const int g = blockIdx.x;
    // lower_bound(batch, g) and lower_bound(batch, g+1)
    int lo = 0, hi = n;
    while (lo < hi) { int m = (lo + hi) >> 1; if (batch[m] < g) lo = m + 1; else hi = m; }
    const int start = lo;
    lo = start; hi = n;
    while (lo < hi) { int m = (lo + hi) >> 1; if (batch[m] < g + 1) lo = m + 1; else hi = m; }
    const int end = lo;

    __shared__ float part[256];
    const int f = threadIdx.x & 31;
    const int r = threadIdx.x >> 5;  // 0..7
    float acc = 0.f;
    for (int i = start + r; i < end; i += 8) acc += h[(size_t)i * 32 + f];
    part[threadIdx.x] = acc;
    __syncthreads();
    if (threadIdx.x < 32) {
        float s = 0.f;
#pragma unroll
        for (int q = 0; q < 8; ++q) s += part[q * 32 + f];
        float inv = 1.0f / fmaxf((float)(end - start), 1.0f);
        pooled[g * 32 + f] = s * inv;
    }
}

__global__ void final_kernel(const float* __restrict__ pooled,
                             const float* __restrict__ Wl, const float* __restrict__ bl,
                             float* __restrict__ out) {
    int idx = blockIdx.x * blockDim.x + threadIdx.x;  // [0, 64*768)
    int g = idx / OUTD, o = idx - g * OUTD;
    float acc = bl[o];
#pragma unroll
    for (int k = 0; k < 32; ++k)
        acc = fmaf(pooled[g * 32 + k], Wl[k * OUTD + o], acc);
    out[idx] = acc;
}

// ---------------------------------------------------------------------------
extern "C" void kernel_launch(void* const* d_in, const int* in_sizes, int n_in,
                              void* d_out, int out_size, void* d_ws, size_t ws_size,
                              hipStream_t stream) {
    const float* x = (const float*)d_in[0];
    const int* eidx = (const int*)d_in[1];
    const float* ea = (const float*)d_in[2];
    const int* batch = (const int*)d_in[3];
    const float* W1 = (const float*)d_in[4];
    const float* b1 = (const float*)d_in[5];
    const float* W2 = (const float*)d_in[6];
    const float* b2 = (const float*)d_in[7];
    const float* W3 = (const float*)d_in[8];
    const float* b3 = (const float*)d_in[9];
    const float* Wl = (const float*)d_in[10];
    const float* bl = (const float*)d_in[11];
    const int* src = eidx;
    const int* dst = eidx + NE;

    char* p = (char*)d_ws;
    auto take = [&](size_t bytes) {
        char* r = p;
        p += (bytes + 255) & ~(size_t)255;
        return r;
    };
    float* deg = (float*)take(NN * 4);
    float* dinv = (float*)take(NN * 4);
    float* invdeg = (float*)take(NN * 4);
    int* hist = (int*)take(NN * 4);
    int* rowptr = (int*)take((NN + 1) * 4);
    int* cursor = (int*)take(NN * 4);
    int* esrc = (int*)take((size_t)NE * 4);
    float* ecoef = (float*)take((size_t)NE * 4);
    float* pooled = (float*)take(NG * 32 * 4);
    unsigned int* wmax = (unsigned int*)take(4);
    float* bufA = (float*)take((size_t)NN * 128 * 4);
    float* bufB = (float*)take((size_t)NN * 128 * 4);

    const int nblk = (NN + 255) / 256;   // 196
    const int eblk = (NE + 255) / 256;   // 3125

    init_kernel<<<nblk, 256, 0, stream>>>(deg, hist, wmax, NN);
    max_kernel<<<128, 256, 0, stream>>>(ea, wmax, NE);
    deg_hist_kernel<<<eblk, 256, 0, stream>>>(dst, ea, wmax, deg, hist, NE);
    dinv_kernel<<<nblk, 256, 0, stream>>>(deg, dinv, invdeg, NN);
    scan_kernel<<<1, 1024, 0, stream>>>(hist, rowptr, cursor, NN);
    scatter_kernel<<<eblk, 256, 0, stream>>>(src, dst, ea, wmax, dinv, cursor, esrc, ecoef, NE);

    // layer 1: H = x @ W1 (128->128), then aggregate+relu
    gemm_kernel<128, 128, 64><<<dim3((NN + 63) / 64, 2), 256, 0, stream>>>(x, W1, bufA, NN);
    agg_kernel<128><<<(NN + 3) / 4, 256, 0, stream>>>(bufA, rowptr, esrc, ecoef, invdeg, b1, bufB, NN);
    // layer 2: 128->64
    gemm_kernel<128, 64, 64><<<dim3((NN + 63) / 64, 1), 256, 0, stream>>>(bufB, W2, bufA, NN);
    agg_kernel<64><<<(NN + 3) / 4, 256, 0, stream>>>(bufA, rowptr, esrc, ecoef, invdeg, b2, bufB, NN);
    // layer 3: 64->32
    gemm_kernel<64, 32, 32><<<dim3((NN + 127) / 128, 1), 256, 0, stream>>>(bufB, W3, bufA, NN);
    agg_kernel<32><<<(NN + 7) / 8, 256, 0, stream>>>(bufA, rowptr, esrc, ecoef, invdeg, b3, bufB, NN);

    pool2_kernel<<<NG, 256, 0, stream>>>(bufB, batch, pooled, NN);
    final_kernel<<<(NG * OUTD) / 256, 256, 0, stream>>>(pooled, Wl, bl, (float*)d_out);
}

// Round 3
// 460.314 us; speedup vs baseline: 2.5229x; 1.2793x over previous
//
#include <hip/hip_runtime.h>
#include <hip/hip_bf16.h>

// Problem constants (fixed by the reference)
#define NN 50000
#define NE 800000
#define NG 64
#define IND 128
#define HID 128
#define OUTD 768

// ---------------------------------------------------------------------------
// init: deg=1, hist=0, wmax=0
__global__ void init_kernel(float* deg, int* hist, unsigned int* wmax, int n) {
    int i = blockIdx.x * blockDim.x + threadIdx.x;
    if (i < n) { deg[i] = 1.0f; hist[i] = 0; }
    if (i == 0) *wmax = 0u;
}

// max(edge_attr) via block reduce + uint atomicMax (valid: all values > 0)
__global__ void max_kernel(const float* __restrict__ ea, unsigned int* wmax, int nE) {
    __shared__ float red[256];
    float m = 0.0f;
    for (int i = blockIdx.x * blockDim.x + threadIdx.x; i < nE;
         i += gridDim.x * blockDim.x)
        m = fmaxf(m, ea[i]);
    red[threadIdx.x] = m;
    __syncthreads();
    for (int off = 128; off > 0; off >>= 1) {
        if (threadIdx.x < off)
            red[threadIdx.x] = fmaxf(red[threadIdx.x], red[threadIdx.x + off]);
        __syncthreads();
    }
    if (threadIdx.x == 0) atomicMax(wmax, __float_as_uint(red[0]));
}

// deg[dst] += w ; hist[dst] += 1
__global__ void deg_hist_kernel(const int* __restrict__ dst, const float* __restrict__ ea,
                                const unsigned int* __restrict__ wmax,
                                float* deg, int* hist, int nE) {
    int e = blockIdx.x * blockDim.x + threadIdx.x;
    if (e >= nE) return;
    float rw = 1.0f / __uint_as_float(*wmax);
    int d = dst[e];
    atomicAdd(&deg[d], ea[e] * rw);
    atomicAdd(&hist[d], 1);
}

__global__ void dinv_kernel(const float* __restrict__ deg, float* dinv, float* invdeg, int n) {
    int i = blockIdx.x * blockDim.x + threadIdx.x;
    if (i >= n) return;
    float d = deg[i];
    dinv[i] = rsqrtf(d);
    invdeg[i] = 1.0f / d;
}

// ---------------------------------------------------------------------------
// Hierarchical exclusive scan of hist -> rowptr (+ copy in cursor).
// scan1: per-block (256-wide) sums.  scan2: 1-block scan of block sums,
// writes grand total to rowptr[n].  scan3: per-block exclusive scan + offset.
__global__ __launch_bounds__(256) void scan1_kernel(const int* __restrict__ hist,
                                                    int* __restrict__ blocksum, int n) {
    __shared__ int red[256];
    int i = blockIdx.x * 256 + threadIdx.x;
    red[threadIdx.x] = (i < n) ? hist[i] : 0;
    __syncthreads();
    for (int off = 128; off > 0; off >>= 1) {
        if (threadIdx.x < off) red[threadIdx.x] += red[threadIdx.x + off];
        __syncthreads();
    }
    if (threadIdx.x == 0) blocksum[blockIdx.x] = red[0];
}

__global__ __launch_bounds__(256) void scan2_kernel(const int* __restrict__ blocksum,
                                                    int* __restrict__ blockoff,
                                                    int* __restrict__ total_out, int nb) {
    __shared__ int s[256];
    const int tid = threadIdx.x;
    int v = (tid < nb) ? blocksum[tid] : 0;
    s[tid] = v;
    __syncthreads();
    for (int off = 1; off < 256; off <<= 1) {
        int t = (tid >= off) ? s[tid - off] : 0;
        __syncthreads();
        s[tid] += t;
        __syncthreads();
    }
    if (tid < nb) blockoff[tid] = s[tid] - v;
    if (tid == nb - 1) *total_out = s[tid];
}

__global__ __launch_bounds__(256) void scan3_kernel(const int* __restrict__ hist,
                                                    const int* __restrict__ blockoff,
                                                    int* __restrict__ rowptr,
                                                    int* __restrict__ cursor, int n) {
    __shared__ int s[256];
    const int tid = threadIdx.x;
    int i = blockIdx.x * 256 + tid;
    int v = (i < n) ? hist[i] : 0;
    s[tid] = v;
    __syncthreads();
    for (int off = 1; off < 256; off <<= 1) {
        int t = (tid >= off) ? s[tid - off] : 0;
        __syncthreads();
        s[tid] += t;
        __syncthreads();
    }
    if (i < n) {
        int ex = blockoff[blockIdx.x] + s[tid] - v;
        rowptr[i] = ex;
        cursor[i] = ex;
    }
}

// bucket edges by dst; store packed {src, coef} (single 8B write per edge)
__global__ void scatter_kernel(const int* __restrict__ src, const int* __restrict__ dst,
                               const float* __restrict__ ea,
                               const unsigned int* __restrict__ wmax,
                               const float* __restrict__ dinv,
                               int* cursor, int2* __restrict__ epack, int nE) {
    int e = blockIdx.x * blockDim.x + threadIdx.x;
    if (e >= nE) return;
    float rw = 1.0f / __uint_as_float(*wmax);
    int s = src[e], d = dst[e];
    int pos = atomicAdd(&cursor[d], 1);
    float c = dinv[s] * (ea[e] * rw) * dinv[d];
    epack[pos] = make_int2(s, __float_as_int(c));
}

// ---------------------------------------------------------------------------
// GEMM: Y[N,D-slice] = X[N,K] @ W[K,D], fp32 vector ALU, LDS tiled,
// 4 rows x 4 cols per thread. X tile stored k-grouped as float4 (aligned b128).
template <int K, int D, int DT>
__global__ __launch_bounds__(256) void gemm_kernel(const float* __restrict__ X,
                                                   const float* __restrict__ W,
                                                   float* __restrict__ Y, int nRows) {
    constexpr int CG = DT / 4;       // col groups
    constexpr int RT = 1024 / CG;    // rows per block
    constexpr int KG = K / 4;        // k groups
    constexpr int XS = RT + 1;       // XsT4 row stride (float4 units) — breaks bank clash
    __shared__ float4 XsT4[KG * XS];
    __shared__ float Ws[K * DT];

    const int tid = threadIdx.x;
    const int rowbase = blockIdx.x * RT;
    const int cbase = blockIdx.y * DT;

    for (int q = tid; q < K * DT / 4; q += 256) {
        int kw = q / CG;
        int c0 = (q - kw * CG) * 4;
        *(float4*)&Ws[kw * DT + c0] = *(const float4*)&W[kw * D + cbase + c0];
    }
    for (int q = tid; q < RT * KG; q += 256) {
        int r = q / KG;
        int kg = q - r * KG;
        int grow = rowbase + r;
        float4 xv = make_float4(0.f, 0.f, 0.f, 0.f);
        if (grow < nRows) xv = *(const float4*)&X[(size_t)grow * K + kg * 4];
        XsT4[kg * XS + r] = xv;
    }
    __syncthreads();

    const int c0 = (tid % CG) * 4;
    const int r0 = (tid / CG) * 4;
    float acc[4][4] = {};
#pragma unroll 4
    for (int kg = 0; kg < KG; ++kg) {
        float4 xr[4], wk[4];
#pragma unroll
        for (int i = 0; i < 4; ++i) xr[i] = XsT4[kg * XS + r0 + i];
#pragma unroll
        for (int m = 0; m < 4; ++m) wk[m] = *(const float4*)&Ws[(kg * 4 + m) * DT + c0];
#pragma unroll
        for (int i = 0; i < 4; ++i) {
            float xi[4] = {xr[i].x, xr[i].y, xr[i].z, xr[i].w};
#pragma unroll
            for (int m = 0; m < 4; ++m) {
                acc[i][0] = fmaf(xi[m], wk[m].x, acc[i][0]);
                acc[i][1] = fmaf(xi[m], wk[m].y, acc[i][1]);
                acc[i][2] = fmaf(xi[m], wk[m].z, acc[i][2]);
                acc[i][3] = fmaf(xi[m], wk[m].w, acc[i][3]);
            }
        }
    }
#pragma unroll
    for (int i = 0; i < 4; ++i) {
        int grow = rowbase + r0 + i;
        if (grow < nRows)
            *(float4*)&Y[(size_t)grow * D + cbase + c0] =
                make_float4(acc[i][0], acc[i][1], acc[i][2], acc[i][3]);
    }
}

// ---------------------------------------------------------------------------
// Aggregation: out[n] = relu( sum_in coef*H[src] + invdeg[n]*H[n] + b )
// Edge descriptors packed {src, coef}; edge loop manually 2x unrolled so two
// H-row gathers are in flight per iteration.
template <int D>
__global__ __launch_bounds__(256) void agg_kernel(const float* __restrict__ H,
                                                  const int* __restrict__ rowptr,
                                                  const int2* __restrict__ epack,
                                                  const float* __restrict__ invdeg,
                                                  const float* __restrict__ bias,
                                                  float* __restrict__ out, int nNodes) {
    const int lane = threadIdx.x & 63;
    const int wid = (blockIdx.x << 2) | (threadIdx.x >> 6);
    if constexpr (D >= 64) {
        const int n = __builtin_amdgcn_readfirstlane(wid);
        if (n >= nNodes) return;
        constexpr int V = D / 64;  // 2 or 1
        const int f = lane * V;
        const int s0 = rowptr[n], s1 = rowptr[n + 1];
        if constexpr (V == 2) {
            float a0 = 0.f, a1 = 0.f;
            int e = s0;
            for (; e + 1 < s1; e += 2) {
                const int2 p0 = epack[e];
                const int2 p1 = epack[e + 1];
                float2 h0 = *(const float2*)(H + (size_t)p0.x * D + f);
                float2 h1 = *(const float2*)(H + (size_t)p1.x * D + f);
                const float c0 = __int_as_float(p0.y);
                const float c1 = __int_as_float(p1.y);
                a0 = fmaf(c0, h0.x, a0);
                a1 = fmaf(c0, h0.y, a1);
                a0 = fmaf(c1, h1.x, a0);
                a1 = fmaf(c1, h1.y, a1);
            }
            if (e < s1) {
                const int2 p0 = epack[e];
                float2 h0 = *(const float2*)(H + (size_t)p0.x * D + f);
                const float c0 = __int_as_float(p0.y);
                a0 = fmaf(c0, h0.x, a0);
                a1 = fmaf(c0, h0.y, a1);
            }
            const float id = invdeg[n];
            float2 hn = *(const float2*)(H + (size_t)n * D + f);
            float2 bv = *(const float2*)(bias + f);
            a0 = fmaxf(fmaf(id, hn.x, a0) + bv.x, 0.f);
            a1 = fmaxf(fmaf(id, hn.y, a1) + bv.y, 0.f);
            *(float2*)(out + (size_t)n * D + f) = make_float2(a0, a1);
        } else {
            float a0 = 0.f;
            int e = s0;
            for (; e + 1 < s1; e += 2) {
                const int2 p0 = epack[e];
                const int2 p1 = epack[e + 1];
                float h0 = H[(size_t)p0.x * D + f];
                float h1 = H[(size_t)p1.x * D + f];
                a0 = fmaf(__int_as_float(p0.y), h0, a0);
                a0 = fmaf(__int_as_float(p1.y), h1, a0);
            }
            if (e < s1) {
                const int2 p0 = epack[e];
                a0 = fmaf(__int_as_float(p0.y), H[(size_t)p0.x * D + f], a0);
            }
            a0 = fmaxf(fmaf(invdeg[n], H[(size_t)n * D + f], a0) + bias[f], 0.f);
            out[(size_t)n * D + f] = a0;
        }
    } else {  // D == 32
        const int sub = lane >> 5;
        const int f = lane & 31;
        const int n = wid * 2 + sub;
        if (n >= nNodes) return;
        float a0 = 0.f;
        const int s0 = rowptr[n], s1 = rowptr[n + 1];
        int e = s0;
        for (; e + 1 < s1; e += 2) {
            const int2 p0 = epack[e];
            const int2 p1 = epack[e + 1];
            float h0 = H[(size_t)p0.x * D + f];
            float h1 = H[(size_t)p1.x * D + f];
            a0 = fmaf(__int_as_float(p0.y), h0, a0);
            a0 = fmaf(__int_as_float(p1.y), h1, a0);
        }
        if (e < s1) {
            const int2 p0 = epack[e];
            a0 = fmaf(__int_as_float(p0.y), H[(size_t)p0.x * D + f], a0);
        }
        a0 = fmaxf(fmaf(invdeg[n], H[(size_t)n * D + f], a0) + bias[f], 0.f);
        out[(size_t)n * D + f] = a0;
    }
}

// ---------------------------------------------------------------------------
// Pool: batch is SORTED -> one block per graph, binary search the node range,
// strided coalesced sum, LDS reduce, write pooled[g][f] = sum / max(cnt,1).
__global__ __launch_bounds__(256) void pool2_kernel(const float* __restrict__ h,
                                                    const int* __restrict__ batch,
                                                    float* __restrict__ pooled, int n) {
    const int g = blockIdx.x;
    int lo = 0, hi = n;
    while (lo < hi) { int m = (lo + hi) >> 1; if (batch[m] < g) lo = m + 1; else hi = m; }
    const int start = lo;
    lo = start; hi = n;
    while (lo < hi) { int m = (lo + hi) >> 1; if (batch[m] < g + 1) lo = m + 1; else hi = m; }
    const int end = lo;

    __shared__ float part[256];
    const int f = threadIdx.x & 31;
    const int r = threadIdx.x >> 5;  // 0..7
    float acc = 0.f;
    for (int i = start + r; i < end; i += 8) acc += h[(size_t)i * 32 + f];
    part[threadIdx.x] = acc;
    __syncthreads();
    if (threadIdx.x < 32) {
        float s = 0.f;
#pragma unroll
        for (int q = 0; q < 8; ++q) s += part[q * 32 + f];
        float inv = 1.0f / fmaxf((float)(end - start), 1.0f);
        pooled[g * 32 + f] = s * inv;
    }
}

__global__ void final_kernel(const float* __restrict__ pooled,
                             const float* __restrict__ Wl, const float* __restrict__ bl,
                             float* __restrict__ out) {
    int idx = blockIdx.x * blockDim.x + threadIdx.x;  // [0, 64*768)
    int g = idx / OUTD, o = idx - g * OUTD;
    float acc = bl[o];
#pragma unroll
    for (int k = 0; k < 32; ++k)
        acc = fmaf(pooled[g * 32 + k], Wl[k * OUTD + o], acc);
    out[idx] = acc;
}

// ---------------------------------------------------------------------------
extern "C" void kernel_launch(void* const* d_in, const int* in_sizes, int n_in,
                              void* d_out, int out_size, void* d_ws, size_t ws_size,
                              hipStream_t stream) {
    const float* x = (const float*)d_in[0];
    const int* eidx = (const int*)d_in[1];
    const float* ea = (const float*)d_in[2];
    const int* batch = (const int*)d_in[3];
    const float* W1 = (const float*)d_in[4];
    const float* b1 = (const float*)d_in[5];
    const float* W2 = (const float*)d_in[6];
    const float* b2 = (const float*)d_in[7];
    const float* W3 = (const float*)d_in[8];
    const float* b3 = (const float*)d_in[9];
    const float* Wl = (const float*)d_in[10];
    const float* bl = (const float*)d_in[11];
    const int* src = eidx;
    const int* dst = eidx + NE;

    char* p = (char*)d_ws;
    auto take = [&](size_t bytes) {
        char* r = p;
        p += (bytes + 255) & ~(size_t)255;
        return r;
    };
    float* deg = (float*)take(NN * 4);
    float* dinv = (float*)take(NN * 4);
    float* invdeg = (float*)take(NN * 4);
    int* hist = (int*)take(NN * 4);
    int* rowptr = (int*)take((NN + 1) * 4);
    int* cursor = (int*)take(NN * 4);
    int* blocksum = (int*)take(256 * 4);
    int* blockoff = (int*)take(256 * 4);
    int2* epack = (int2*)take((size_t)NE * 8);
    float* pooled = (float*)take(NG * 32 * 4);
    unsigned int* wmax = (unsigned int*)take(4);
    float* bufA = (float*)take((size_t)NN * 128 * 4);
    float* bufB = (float*)take((size_t)NN * 128 * 4);

    const int nblk = (NN + 255) / 256;   // 196
    const int eblk = (NE + 255) / 256;   // 3125

    init_kernel<<<nblk, 256, 0, stream>>>(deg, hist, wmax, NN);
    max_kernel<<<128, 256, 0, stream>>>(ea, wmax, NE);
    deg_hist_kernel<<<eblk, 256, 0, stream>>>(dst, ea, wmax, deg, hist, NE);
    dinv_kernel<<<nblk, 256, 0, stream>>>(deg, dinv, invdeg, NN);
    scan1_kernel<<<nblk, 256, 0, stream>>>(hist, blocksum, NN);
    scan2_kernel<<<1, 256, 0, stream>>>(blocksum, blockoff, &rowptr[NN], nblk);
    scan3_kernel<<<nblk, 256, 0, stream>>>(hist, blockoff, rowptr, cursor, NN);
    scatter_kernel<<<eblk, 256, 0, stream>>>(src, dst, ea, wmax, dinv, cursor, epack, NE);

    // layer 1: H = x @ W1 (128->128), then aggregate+relu
    gemm_kernel<128, 128, 64><<<dim3((NN + 63) / 64, 2), 256, 0, stream>>>(x, W1, bufA, NN);
    agg_kernel<128><<<(NN + 3) / 4, 256, 0, stream>>>(bufA, rowptr, epack, invdeg, b1, bufB, NN);
    // layer 2: 128->64
    gemm_kernel<128, 64, 64><<<dim3((NN + 63) / 64, 1), 256, 0, stream>>>(bufB, W2, bufA, NN);
    agg_kernel<64><<<(NN + 3) / 4, 256, 0, stream>>>(bufA, rowptr, epack, invdeg, b2, bufB, NN);
    // layer 3: 64->32
    gemm_kernel<64, 32, 32><<<dim3((NN + 127) / 128, 1), 256, 0, stream>>>(bufB, W3, bufA, NN);
    agg_kernel<32><<<(NN + 7) / 8, 256, 0, stream>>>(bufA, rowptr, epack, invdeg, b3, bufB, NN);

    pool2_kernel<<<NG, 256, 0, stream>>>(bufB, batch, pooled, NN);
    final_kernel<<<(NG * OUTD) / 256, 256, 0, stream>>>(pooled, Wl, bl, (float*)d_out);
}

// Round 4
// 396.587 us; speedup vs baseline: 2.9283x; 1.1607x over previous
//
#include <hip/hip_runtime.h>
#include <hip/hip_bf16.h>

// Problem constants (fixed by the reference)
#define NN 50000
#define NE 800000
#define NG 64
#define OUTD 768

// fused1 block-range dispatch
#define MAXB 128                    // max-reduce blocks
#define RANKB ((NE + 255) / 256)    // 3125 rank blocks
#define G1X ((NN + 63) / 64)        // 782
#define G1Y 2
#define G1B (G1X * G1Y)             // 1564 gemm1 blocks

// ---------------------------------------------------------------------------
// GEMM body: Y[N,D-slice] = X[N,K] @ W[K,D], fp32 vector ALU, LDS tiled,
// 4 rows x 4 cols per thread. X tile stored k-grouped as float4.
template <int K, int D, int DT>
__device__ __forceinline__ void gemm_body(const float* __restrict__ X,
                                          const float* __restrict__ W,
                                          float* __restrict__ Y, int nRows,
                                          int bx, int by) {
    constexpr int CG = DT / 4;       // col groups
    constexpr int RT = 1024 / CG;    // rows per block
    constexpr int KG = K / 4;        // k groups
    constexpr int XS = RT + 1;       // padded stride breaks bank clash
    __shared__ float4 XsT4[KG * XS];
    __shared__ float Ws[K * DT];

    const int tid = threadIdx.x;
    const int rowbase = bx * RT;
    const int cbase = by * DT;

    for (int q = tid; q < K * DT / 4; q += 256) {
        int kw = q / CG;
        int c0 = (q - kw * CG) * 4;
        *(float4*)&Ws[kw * DT + c0] = *(const float4*)&W[kw * D + cbase + c0];
    }
    for (int q = tid; q < RT * KG; q += 256) {
        int r = q / KG;
        int kg = q - r * KG;
        int grow = rowbase + r;
        float4 xv = make_float4(0.f, 0.f, 0.f, 0.f);
        if (grow < nRows) xv = *(const float4*)&X[(size_t)grow * K + kg * 4];
        XsT4[kg * XS + r] = xv;
    }
    __syncthreads();

    const int c0 = (tid % CG) * 4;
    const int r0 = (tid / CG) * 4;
    float acc[4][4] = {};
#pragma unroll 4
    for (int kg = 0; kg < KG; ++kg) {
        float4 xr[4], wk[4];
#pragma unroll
        for (int i = 0; i < 4; ++i) xr[i] = XsT4[kg * XS + r0 + i];
#pragma unroll
        for (int m = 0; m < 4; ++m) wk[m] = *(const float4*)&Ws[(kg * 4 + m) * DT + c0];
#pragma unroll
        for (int i = 0; i < 4; ++i) {
            float xi[4] = {xr[i].x, xr[i].y, xr[i].z, xr[i].w};
#pragma unroll
            for (int m = 0; m < 4; ++m) {
                acc[i][0] = fmaf(xi[m], wk[m].x, acc[i][0]);
                acc[i][1] = fmaf(xi[m], wk[m].y, acc[i][1]);
                acc[i][2] = fmaf(xi[m], wk[m].z, acc[i][2]);
                acc[i][3] = fmaf(xi[m], wk[m].w, acc[i][3]);
            }
        }
    }
#pragma unroll
    for (int i = 0; i < 4; ++i) {
        int grow = rowbase + r0 + i;
        if (grow < nRows)
            *(float4*)&Y[(size_t)grow * D + cbase + c0] =
                make_float4(acc[i][0], acc[i][1], acc[i][2], acc[i][3]);
    }
}

template <int K, int D, int DT>
__global__ __launch_bounds__(256) void gemm_kernel(const float* __restrict__ X,
                                                   const float* __restrict__ W,
                                                   float* __restrict__ Y, int nRows) {
    gemm_body<K, D, DT>(X, W, Y, nRows, blockIdx.x, blockIdx.y);
}

// ---------------------------------------------------------------------------
// fused1: [0,MAXB) -> max(edge_attr); [MAXB,MAXB+RANKB) -> rank/hist count;
// rest -> gemm1 (x @ W1). All three are mutually independent.
__global__ __launch_bounds__(256) void fused1_kernel(const float* __restrict__ ea,
                                                     unsigned int* wmax,
                                                     const int* __restrict__ dst,
                                                     int* hist, int* __restrict__ rank,
                                                     const float* __restrict__ x,
                                                     const float* __restrict__ W1,
                                                     float* __restrict__ bufA) {
    const int b = blockIdx.x;
    if (b < MAXB) {
        __shared__ float red[256];
        float m = 0.0f;
        for (int i = b * 256 + threadIdx.x; i < NE; i += MAXB * 256)
            m = fmaxf(m, ea[i]);
        red[threadIdx.x] = m;
        __syncthreads();
        for (int off = 128; off > 0; off >>= 1) {
            if (threadIdx.x < off)
                red[threadIdx.x] = fmaxf(red[threadIdx.x], red[threadIdx.x + off]);
            __syncthreads();
        }
        if (threadIdx.x == 0) atomicMax(wmax, __float_as_uint(red[0]));
    } else if (b < MAXB + RANKB) {
        int e = (b - MAXB) * 256 + threadIdx.x;
        if (e < NE) rank[e] = atomicAdd(&hist[dst[e]], 1);
    } else {
        int g = b - MAXB - RANKB;
        gemm_body<128, 128, 64>(x, W1, bufA, NN, g % G1X, g / G1X);
    }
}

// ---------------------------------------------------------------------------
// Hierarchical exclusive scan of hist -> rowptr.
__global__ __launch_bounds__(256) void scan1_kernel(const int* __restrict__ hist,
                                                    int* __restrict__ blocksum, int n) {
    __shared__ int red[256];
    int i = blockIdx.x * 256 + threadIdx.x;
    red[threadIdx.x] = (i < n) ? hist[i] : 0;
    __syncthreads();
    for (int off = 128; off > 0; off >>= 1) {
        if (threadIdx.x < off) red[threadIdx.x] += red[threadIdx.x + off];
        __syncthreads();
    }
    if (threadIdx.x == 0) blocksum[blockIdx.x] = red[0];
}

__global__ __launch_bounds__(256) void scan2_kernel(const int* __restrict__ blocksum,
                                                    int* __restrict__ blockoff,
                                                    int* __restrict__ total_out, int nb) {
    __shared__ int s[256];
    const int tid = threadIdx.x;
    int v = (tid < nb) ? blocksum[tid] : 0;
    s[tid] = v;
    __syncthreads();
    for (int off = 1; off < 256; off <<= 1) {
        int t = (tid >= off) ? s[tid - off] : 0;
        __syncthreads();
        s[tid] += t;
        __syncthreads();
    }
    if (tid < nb) blockoff[tid] = s[tid] - v;
    if (tid == nb - 1) *total_out = s[tid];
}

__global__ __launch_bounds__(256) void scan3_kernel(const int* __restrict__ hist,
                                                    const int* __restrict__ blockoff,
                                                    int* __restrict__ rowptr, int n) {
    __shared__ int s[256];
    const int tid = threadIdx.x;
    int i = blockIdx.x * 256 + tid;
    int v = (i < n) ? hist[i] : 0;
    s[tid] = v;
    __syncthreads();
    for (int off = 1; off < 256; off <<= 1) {
        int t = (tid >= off) ? s[tid - off] : 0;
        __syncthreads();
        s[tid] += t;
        __syncthreads();
    }
    if (i < n) rowptr[i] = blockoff[blockIdx.x] + s[tid] - v;
}

// ---------------------------------------------------------------------------
// Atomic-free scatter: pos = rowptr[dst] + rank[e]; store {src, raw ea}.
__global__ void scatter2_kernel(const int* __restrict__ src, const int* __restrict__ dst,
                                const float* __restrict__ ea,
                                const int* __restrict__ rowptr,
                                const int* __restrict__ rank,
                                int2* __restrict__ epack, int nE) {
    int e = blockIdx.x * blockDim.x + threadIdx.x;
    if (e >= nE) return;
    int pos = rowptr[dst[e]] + rank[e];
    epack[pos] = make_int2(src[e], __float_as_int(ea[e]));
}

// deg from contiguous CSR segments (no atomics): deg = 1 + rw * sum(ea)
__global__ void deg_kernel(const int2* __restrict__ epack, const int* __restrict__ rowptr,
                           const unsigned int* __restrict__ wmax,
                           float* __restrict__ dinv, float* __restrict__ invdeg, int n) {
    int i = blockIdx.x * blockDim.x + threadIdx.x;
    if (i >= n) return;
    float rw = 1.0f / __uint_as_float(*wmax);
    int s0 = rowptr[i], s1 = rowptr[i + 1];
    float s = 0.f;
    for (int e = s0; e < s1; ++e) s += __int_as_float(epack[e].y);
    float d = fmaf(s, rw, 1.0f);
    dinv[i] = rsqrtf(d);
    invdeg[i] = 1.0f / d;
}

// rewrite epack.y: raw ea -> layer-invariant coefficient
__global__ void coef_kernel(int2* __restrict__ epack, const int* __restrict__ rowptr,
                            const float* __restrict__ dinv,
                            const unsigned int* __restrict__ wmax, int n) {
    int i = blockIdx.x * blockDim.x + threadIdx.x;
    if (i >= n) return;
    float rw = 1.0f / __uint_as_float(*wmax);
    float di = dinv[i];
    int s0 = rowptr[i], s1 = rowptr[i + 1];
    for (int e = s0; e < s1; ++e) {
        int2 p = epack[e];
        p.y = __float_as_int(dinv[p.x] * (__int_as_float(p.y) * rw) * di);
        epack[e] = p;
    }
}

// ---------------------------------------------------------------------------
// Aggregation: out[n] = relu( sum_in coef*H[src] + invdeg[n]*H[n] + b )
template <int D>
__global__ __launch_bounds__(256) void agg_kernel(const float* __restrict__ H,
                                                  const int* __restrict__ rowptr,
                                                  const int2* __restrict__ epack,
                                                  const float* __restrict__ invdeg,
                                                  const float* __restrict__ bias,
                                                  float* __restrict__ out, int nNodes) {
    const int lane = threadIdx.x & 63;
    const int wid = (blockIdx.x << 2) | (threadIdx.x >> 6);
    if constexpr (D >= 64) {
        const int n = __builtin_amdgcn_readfirstlane(wid);
        if (n >= nNodes) return;
        constexpr int V = D / 64;  // 2 or 1
        const int f = lane * V;
        const int s0 = rowptr[n], s1 = rowptr[n + 1];
        if constexpr (V == 2) {
            float a0 = 0.f, a1 = 0.f;
            int e = s0;
            for (; e + 1 < s1; e += 2) {
                const int2 p0 = epack[e];
                const int2 p1 = epack[e + 1];
                float2 h0 = *(const float2*)(H + (size_t)p0.x * D + f);
                float2 h1 = *(const float2*)(H + (size_t)p1.x * D + f);
                const float c0 = __int_as_float(p0.y);
                const float c1 = __int_as_float(p1.y);
                a0 = fmaf(c0, h0.x, a0);
                a1 = fmaf(c0, h0.y, a1);
                a0 = fmaf(c1, h1.x, a0);
                a1 = fmaf(c1, h1.y, a1);
            }
            if (e < s1) {
                const int2 p0 = epack[e];
                float2 h0 = *(const float2*)(H + (size_t)p0.x * D + f);
                const float c0 = __int_as_float(p0.y);
                a0 = fmaf(c0, h0.x, a0);
                a1 = fmaf(c0, h0.y, a1);
            }
            const float id = invdeg[n];
            float2 hn = *(const float2*)(H + (size_t)n * D + f);
            float2 bv = *(const float2*)(bias + f);
            a0 = fmaxf(fmaf(id, hn.x, a0) + bv.x, 0.f);
            a1 = fmaxf(fmaf(id, hn.y, a1) + bv.y, 0.f);
            *(float2*)(out + (size_t)n * D + f) = make_float2(a0, a1);
        } else {
            float a0 = 0.f;
            int e = s0;
            for (; e + 1 < s1; e += 2) {
                const int2 p0 = epack[e];
                const int2 p1 = epack[e + 1];
                float h0 = H[(size_t)p0.x * D + f];
                float h1 = H[(size_t)p1.x * D + f];
                a0 = fmaf(__int_as_float(p0.y), h0, a0);
                a0 = fmaf(__int_as_float(p1.y), h1, a0);
            }
            if (e < s1) {
                const int2 p0 = epack[e];
                a0 = fmaf(__int_as_float(p0.y), H[(size_t)p0.x * D + f], a0);
            }
            a0 = fmaxf(fmaf(invdeg[n], H[(size_t)n * D + f], a0) + bias[f], 0.f);
            out[(size_t)n * D + f] = a0;
        }
    } else {  // D == 32
        const int sub = lane >> 5;
        const int f = lane & 31;
        const int n = wid * 2 + sub;
        if (n >= nNodes) return;
        float a0 = 0.f;
        const int s0 = rowptr[n], s1 = rowptr[n + 1];
        int e = s0;
        for (; e + 1 < s1; e += 2) {
            const int2 p0 = epack[e];
            const int2 p1 = epack[e + 1];
            float h0 = H[(size_t)p0.x * D + f];
            float h1 = H[(size_t)p1.x * D + f];
            a0 = fmaf(__int_as_float(p0.y), h0, a0);
            a0 = fmaf(__int_as_float(p1.y), h1, a0);
        }
        if (e < s1) {
            const int2 p0 = epack[e];
            a0 = fmaf(__int_as_float(p0.y), H[(size_t)p0.x * D + f], a0);
        }
        a0 = fmaxf(fmaf(invdeg[n], H[(size_t)n * D + f], a0) + bias[f], 0.f);
        out[(size_t)n * D + f] = a0;
    }
}

// ---------------------------------------------------------------------------
// Pool: batch is SORTED -> one block per graph, binary search the range.
__global__ __launch_bounds__(256) void pool2_kernel(const float* __restrict__ h,
                                                    const int* __restrict__ batch,
                                                    float* __restrict__ pooled, int n) {
    const int g = blockIdx.x;
    int lo = 0, hi = n;
    while (lo < hi) { int m = (lo + hi) >> 1; if (batch[m] < g) lo = m + 1; else hi = m; }
    const int start = lo;
    lo = start; hi = n;
    while (lo < hi) { int m = (lo + hi) >> 1; if (batch[m] < g + 1) lo = m + 1; else hi = m; }
    const int end = lo;

    __shared__ float part[256];
    const int f = threadIdx.x & 31;
    const int r = threadIdx.x >> 5;  // 0..7
    float acc = 0.f;
    for (int i = start + r; i < end; i += 8) acc += h[(size_t)i * 32 + f];
    part[threadIdx.x] = acc;
    __syncthreads();
    if (threadIdx.x < 32) {
        float s = 0.f;
#pragma unroll
        for (int q = 0; q < 8; ++q) s += part[q * 32 + f];
        float inv = 1.0f / fmaxf((float)(end - start), 1.0f);
        pooled[g * 32 + f] = s * inv;
    }
}

__global__ void final_kernel(const float* __restrict__ pooled,
                             const float* __restrict__ Wl, const float* __restrict__ bl,
                             float* __restrict__ out) {
    int idx = blockIdx.x * blockDim.x + threadIdx.x;  // [0, 64*768)
    int g = idx / OUTD, o = idx - g * OUTD;
    float acc = bl[o];
#pragma unroll
    for (int k = 0; k < 32; ++k)
        acc = fmaf(pooled[g * 32 + k], Wl[k * OUTD + o], acc);
    out[idx] = acc;
}

// ---------------------------------------------------------------------------
extern "C" void kernel_launch(void* const* d_in, const int* in_sizes, int n_in,
                              void* d_out, int out_size, void* d_ws, size_t ws_size,
                              hipStream_t stream) {
    const float* x = (const float*)d_in[0];
    const int* eidx = (const int*)d_in[1];
    const float* ea = (const float*)d_in[2];
    const int* batch = (const int*)d_in[3];
    const float* W1 = (const float*)d_in[4];
    const float* b1 = (const float*)d_in[5];
    const float* W2 = (const float*)d_in[6];
    const float* b2 = (const float*)d_in[7];
    const float* W3 = (const float*)d_in[8];
    const float* b3 = (const float*)d_in[9];
    const float* Wl = (const float*)d_in[10];
    const float* bl = (const float*)d_in[11];
    const int* src = eidx;
    const int* dst = eidx + NE;

    char* p = (char*)d_ws;
    auto take = [&](size_t bytes) {
        char* r = p;
        p += (bytes + 255) & ~(size_t)255;
        return r;
    };
    float* dinv = (float*)take(NN * 4);
    float* invdeg = (float*)take(NN * 4);
    int* hist = (int*)take(NN * 4);
    int* rowptr = (int*)take((NN + 1) * 4);
    int* rank = (int*)take((size_t)NE * 4);
    int* blocksum = (int*)take(256 * 4);
    int* blockoff = (int*)take(256 * 4);
    int2* epack = (int2*)take((size_t)NE * 8);
    float* pooled = (float*)take(NG * 32 * 4);
    unsigned int* wmax = (unsigned int*)take(4);
    float* bufA = (float*)take((size_t)NN * 128 * 4);
    float* bufB = (float*)take((size_t)NN * 128 * 4);

    const int nblk = (NN + 255) / 256;   // 196
    const int eblk = (NE + 255) / 256;   // 3125

    hipMemsetAsync(hist, 0, NN * 4, stream);
    hipMemsetAsync(wmax, 0, 4, stream);

    // max || rank/hist || gemm1 — mutually independent, co-scheduled
    fused1_kernel<<<MAXB + RANKB + G1B, 256, 0, stream>>>(ea, wmax, dst, hist, rank,
                                                          x, W1, bufA);
    scan1_kernel<<<nblk, 256, 0, stream>>>(hist, blocksum, NN);
    scan2_kernel<<<1, 256, 0, stream>>>(blocksum, blockoff, &rowptr[NN], nblk);
    scan3_kernel<<<nblk, 256, 0, stream>>>(hist, blockoff, rowptr, NN);
    scatter2_kernel<<<eblk, 256, 0, stream>>>(src, dst, ea, rowptr, rank, epack, NE);
    deg_kernel<<<nblk, 256, 0, stream>>>(epack, rowptr, wmax, dinv, invdeg, NN);
    coef_kernel<<<nblk, 256, 0, stream>>>(epack, rowptr, dinv, wmax, NN);

    // layer 1 aggregate (gemm1 already done inside fused1)
    agg_kernel<128><<<(NN + 3) / 4, 256, 0, stream>>>(bufA, rowptr, epack, invdeg, b1, bufB, NN);
    // layer 2: 128->64
    gemm_kernel<128, 64, 64><<<dim3((NN + 63) / 64, 1), 256, 0, stream>>>(bufB, W2, bufA, NN);
    agg_kernel<64><<<(NN + 3) / 4, 256, 0, stream>>>(bufA, rowptr, epack, invdeg, b2, bufB, NN);
    // layer 3: 64->32
    gemm_kernel<64, 32, 32><<<dim3((NN + 127) / 128, 1), 256, 0, stream>>>(bufB, W3, bufA, NN);
    agg_kernel<32><<<(NN + 7) / 8, 256, 0, stream>>>(bufA, rowptr, epack, invdeg, b3, bufB, NN);

    pool2_kernel<<<NG, 256, 0, stream>>>(bufB, batch, pooled, NN);
    final_kernel<<<(NG * OUTD) / 256, 256, 0, stream>>>(pooled, Wl, bl, (float*)d_out);
}

// Round 5
// 381.777 us; speedup vs baseline: 3.0419x; 1.0388x over previous
//
#include <hip/hip_runtime.h>
#include <hip/hip_bf16.h>

// Problem constants (fixed by the reference)
#define NN 50000
#define NE 800000
#define NG 64
#define OUTD 768

// fused1 block-range dispatch: [gemm1 | max | hist-rank]
#define G1X ((NN + 63) / 64)        // 782
#define G1Y 2
#define G1B (G1X * G1Y)             // 1564 gemm1 blocks
#define MAXB 128                    // max-reduce blocks
#define SSEG 64                     // edge segments
#define TTL 4                       // node tiles
#define ESEG (NE / SSEG)            // 12500 edges / segment
#define NTL (NN / TTL)              // 12500 nodes / tile
#define HRB (SSEG * TTL)            // 256 hist-rank blocks

// ---------------------------------------------------------------------------
// GEMM body: Y[N,D-slice] = X[N,K] @ W[K,D], fp32 vector ALU, LDS tiled,
// 4 rows x 4 cols per thread. LDS is caller-provided (dynamic).
template <int K, int DT>
constexpr int gemm_lds_bytes() {
    constexpr int CG = DT / 4;
    constexpr int RT = 1024 / CG;
    constexpr int KG = K / 4;
    constexpr int XS = RT + 1;
    return KG * XS * 16 + K * DT * 4;
}

template <int K, int D, int DT>
__device__ __forceinline__ void gemm_body(char* smem,
                                          const float* __restrict__ X,
                                          const float* __restrict__ W,
                                          float* __restrict__ Y, int nRows,
                                          int bx, int by) {
    constexpr int CG = DT / 4;       // col groups
    constexpr int RT = 1024 / CG;    // rows per block
    constexpr int KG = K / 4;        // k groups
    constexpr int XS = RT + 1;       // padded stride breaks bank clash
    float4* XsT4 = (float4*)smem;
    float* Ws = (float*)(smem + KG * XS * 16);

    const int tid = threadIdx.x;
    const int rowbase = bx * RT;
    const int cbase = by * DT;

    for (int q = tid; q < K * DT / 4; q += 256) {
        int kw = q / CG;
        int c0 = (q - kw * CG) * 4;
        *(float4*)&Ws[kw * DT + c0] = *(const float4*)&W[kw * D + cbase + c0];
    }
    for (int q = tid; q < RT * KG; q += 256) {
        int r = q / KG;
        int kg = q - r * KG;
        int grow = rowbase + r;
        float4 xv = make_float4(0.f, 0.f, 0.f, 0.f);
        if (grow < nRows) xv = *(const float4*)&X[(size_t)grow * K + kg * 4];
        XsT4[kg * XS + r] = xv;
    }
    __syncthreads();

    const int c0 = (tid % CG) * 4;
    const int r0 = (tid / CG) * 4;
    float acc[4][4] = {};
#pragma unroll 4
    for (int kg = 0; kg < KG; ++kg) {
        float4 xr[4], wk[4];
#pragma unroll
        for (int i = 0; i < 4; ++i) xr[i] = XsT4[kg * XS + r0 + i];
#pragma unroll
        for (int m = 0; m < 4; ++m) wk[m] = *(const float4*)&Ws[(kg * 4 + m) * DT + c0];
#pragma unroll
        for (int i = 0; i < 4; ++i) {
            float xi[4] = {xr[i].x, xr[i].y, xr[i].z, xr[i].w};
#pragma unroll
            for (int m = 0; m < 4; ++m) {
                acc[i][0] = fmaf(xi[m], wk[m].x, acc[i][0]);
                acc[i][1] = fmaf(xi[m], wk[m].y, acc[i][1]);
                acc[i][2] = fmaf(xi[m], wk[m].z, acc[i][2]);
                acc[i][3] = fmaf(xi[m], wk[m].w, acc[i][3]);
            }
        }
    }
#pragma unroll
    for (int i = 0; i < 4; ++i) {
        int grow = rowbase + r0 + i;
        if (grow < nRows)
            *(float4*)&Y[(size_t)grow * D + cbase + c0] =
                make_float4(acc[i][0], acc[i][1], acc[i][2], acc[i][3]);
    }
}

template <int K, int D, int DT>
__global__ __launch_bounds__(256) void gemm_kernel(const float* __restrict__ X,
                                                   const float* __restrict__ W,
                                                   float* __restrict__ Y, int nRows) {
    extern __shared__ char smem[];
    gemm_body<K, D, DT>(smem, X, W, Y, nRows, blockIdx.x, blockIdx.y);
}

// ---------------------------------------------------------------------------
// fused1: [0,G1B) gemm1 (x@W1); [G1B,G1B+MAXB) max(edge_attr);
// rest: hist-rank counting via LDS (NO global atomics).
// Block (s,t): count segment s's edges whose dst lies in node-tile t using
// LDS counters; rank[e] = within-(segment,node) rank; dump u16 partial row.
__global__ __launch_bounds__(256) void fused1_kernel(const float* __restrict__ x,
                                                     const float* __restrict__ W1,
                                                     float* __restrict__ bufA,
                                                     const float* __restrict__ ea,
                                                     unsigned int* wmax,
                                                     const int* __restrict__ dst,
                                                     int* __restrict__ rank,
                                                     unsigned short* __restrict__ pcnt) {
    extern __shared__ char smem[];
    const int b = blockIdx.x;
    if (b < G1B) {
        gemm_body<128, 128, 64>(smem, x, W1, bufA, NN, b % G1X, b / G1X);
    } else if (b < G1B + MAXB) {
        float* red = (float*)smem;
        const int bb = b - G1B;
        float m = 0.0f;
        for (int i = bb * 256 + threadIdx.x; i < NE; i += MAXB * 256)
            m = fmaxf(m, ea[i]);
        red[threadIdx.x] = m;
        __syncthreads();
        for (int off = 128; off > 0; off >>= 1) {
            if (threadIdx.x < off)
                red[threadIdx.x] = fmaxf(red[threadIdx.x], red[threadIdx.x + off]);
            __syncthreads();
        }
        if (threadIdx.x == 0) atomicMax(wmax, __float_as_uint(red[0]));
    } else {
        const int b2 = b - G1B - MAXB;   // 0..HRB-1
        const int seg = b2 >> 2;         // TTL == 4
        const int tile = b2 & 3;
        int* lcnt = (int*)smem;          // NTL ints = 50 KB (< gemm's 66 KB)
        for (int i = threadIdx.x; i < NTL; i += 256) lcnt[i] = 0;
        __syncthreads();
        const int base = seg * ESEG;
        const int nlo = tile * NTL;
        for (int e = base + threadIdx.x; e < base + ESEG; e += 256) {
            int d = dst[e] - nlo;
            if ((unsigned)d < (unsigned)NTL)
                rank[e] = atomicAdd(&lcnt[d], 1);   // LDS atomic
        }
        __syncthreads();
        unsigned short* prow = pcnt + (size_t)seg * NN + nlo;
        for (int i = threadIdx.x; i < NTL; i += 256)
            prow[i] = (unsigned short)lcnt[i];
    }
}

// Per-node: exclusive prefix over segments (in place, u16) + total -> hist.
__global__ __launch_bounds__(256) void comb_kernel(unsigned short* __restrict__ pcnt,
                                                   int* __restrict__ hist) {
    int n = blockIdx.x * 256 + threadIdx.x;
    if (n >= NN) return;
    int run = 0;
#pragma unroll
    for (int s = 0; s < SSEG; ++s) {
        size_t idx = (size_t)s * NN + n;
        int v = pcnt[idx];
        pcnt[idx] = (unsigned short)run;
        run += v;
    }
    hist[n] = run;
}

// ---------------------------------------------------------------------------
// Hierarchical exclusive scan of hist -> rowptr.
__global__ __launch_bounds__(256) void scan1_kernel(const int* __restrict__ hist,
                                                    int* __restrict__ blocksum, int n) {
    __shared__ int red[256];
    int i = blockIdx.x * 256 + threadIdx.x;
    red[threadIdx.x] = (i < n) ? hist[i] : 0;
    __syncthreads();
    for (int off = 128; off > 0; off >>= 1) {
        if (threadIdx.x < off) red[threadIdx.x] += red[threadIdx.x + off];
        __syncthreads();
    }
    if (threadIdx.x == 0) blocksum[blockIdx.x] = red[0];
}

__global__ __launch_bounds__(256) void scan2_kernel(const int* __restrict__ blocksum,
                                                    int* __restrict__ blockoff,
                                                    int* __restrict__ total_out, int nb) {
    __shared__ int s[256];
    const int tid = threadIdx.x;
    int v = (tid < nb) ? blocksum[tid] : 0;
    s[tid] = v;
    __syncthreads();
    for (int off = 1; off < 256; off <<= 1) {
        int t = (tid >= off) ? s[tid - off] : 0;
        __syncthreads();
        s[tid] += t;
        __syncthreads();
    }
    if (tid < nb) blockoff[tid] = s[tid] - v;
    if (tid == nb - 1) *total_out = s[tid];
}

__global__ __launch_bounds__(256) void scan3_kernel(const int* __restrict__ hist,
                                                    const int* __restrict__ blockoff,
                                                    int* __restrict__ rowptr, int n) {
    __shared__ int s[256];
    const int tid = threadIdx.x;
    int i = blockIdx.x * 256 + tid;
    int v = (i < n) ? hist[i] : 0;
    s[tid] = v;
    __syncthreads();
    for (int off = 1; off < 256; off <<= 1) {
        int t = (tid >= off) ? s[tid - off] : 0;
        __syncthreads();
        s[tid] += t;
        __syncthreads();
    }
    if (i < n) rowptr[i] = blockoff[blockIdx.x] + s[tid] - v;
}

// ---------------------------------------------------------------------------
// Atomic-free scatter: pos = rowptr[d] + pcnt[seg][d] + rank[e].
__global__ void scat_kernel(const int* __restrict__ src, const int* __restrict__ dst,
                            const float* __restrict__ ea,
                            const int* __restrict__ rowptr,
                            const unsigned short* __restrict__ pcnt,
                            const int* __restrict__ rank,
                            int2* __restrict__ epack, int nE) {
    int e = blockIdx.x * blockDim.x + threadIdx.x;
    if (e >= nE) return;
    int s = e / ESEG;
    int d = dst[e];
    int pos = rowptr[d] + (int)pcnt[(size_t)s * NN + d] + rank[e];
    epack[pos] = make_int2(src[e], __float_as_int(ea[e]));
}

// deg from contiguous CSR segments (no atomics): deg = 1 + rw * sum(ea)
__global__ void deg_kernel(const int2* __restrict__ epack, const int* __restrict__ rowptr,
                           const unsigned int* __restrict__ wmax,
                           float* __restrict__ dinv, float* __restrict__ invdeg, int n) {
    int i = blockIdx.x * blockDim.x + threadIdx.x;
    if (i >= n) return;
    float rw = 1.0f / __uint_as_float(*wmax);
    int s0 = rowptr[i], s1 = rowptr[i + 1];
    float s = 0.f;
    for (int e = s0; e < s1; ++e) s += __int_as_float(epack[e].y);
    float d = fmaf(s, rw, 1.0f);
    dinv[i] = rsqrtf(d);
    invdeg[i] = 1.0f / d;
}

// rewrite epack.y: raw ea -> layer-invariant coefficient
__global__ void coef_kernel(int2* __restrict__ epack, const int* __restrict__ rowptr,
                            const float* __restrict__ dinv,
                            const unsigned int* __restrict__ wmax, int n) {
    int i = blockIdx.x * blockDim.x + threadIdx.x;
    if (i >= n) return;
    float rw = 1.0f / __uint_as_float(*wmax);
    float di = dinv[i];
    int s0 = rowptr[i], s1 = rowptr[i + 1];
    for (int e = s0; e < s1; ++e) {
        int2 p = epack[e];
        p.y = __float_as_int(dinv[p.x] * (__int_as_float(p.y) * rw) * di);
        epack[e] = p;
    }
}

// ---------------------------------------------------------------------------
// Aggregation: out[n] = relu( sum_in coef*H[src] + invdeg[n]*H[n] + b )
template <int D>
__global__ __launch_bounds__(256) void agg_kernel(const float* __restrict__ H,
                                                  const int* __restrict__ rowptr,
                                                  const int2* __restrict__ epack,
                                                  const float* __restrict__ invdeg,
                                                  const float* __restrict__ bias,
                                                  float* __restrict__ out, int nNodes) {
    const int lane = threadIdx.x & 63;
    const int wid = (blockIdx.x << 2) | (threadIdx.x >> 6);
    if constexpr (D >= 64) {
        const int n = __builtin_amdgcn_readfirstlane(wid);
        if (n >= nNodes) return;
        constexpr int V = D / 64;  // 2 or 1
        const int f = lane * V;
        const int s0 = rowptr[n], s1 = rowptr[n + 1];
        if constexpr (V == 2) {
            float a0 = 0.f, a1 = 0.f;
            int e = s0;
            for (; e + 1 < s1; e += 2) {
                const int2 p0 = epack[e];
                const int2 p1 = epack[e + 1];
                float2 h0 = *(const float2*)(H + (size_t)p0.x * D + f);
                float2 h1 = *(const float2*)(H + (size_t)p1.x * D + f);
                const float c0 = __int_as_float(p0.y);
                const float c1 = __int_as_float(p1.y);
                a0 = fmaf(c0, h0.x, a0);
                a1 = fmaf(c0, h0.y, a1);
                a0 = fmaf(c1, h1.x, a0);
                a1 = fmaf(c1, h1.y, a1);
            }
            if (e < s1) {
                const int2 p0 = epack[e];
                float2 h0 = *(const float2*)(H + (size_t)p0.x * D + f);
                const float c0 = __int_as_float(p0.y);
                a0 = fmaf(c0, h0.x, a0);
                a1 = fmaf(c0, h0.y, a1);
            }
            const float id = invdeg[n];
            float2 hn = *(const float2*)(H + (size_t)n * D + f);
            float2 bv = *(const float2*)(bias + f);
            a0 = fmaxf(fmaf(id, hn.x, a0) + bv.x, 0.f);
            a1 = fmaxf(fmaf(id, hn.y, a1) + bv.y, 0.f);
            *(float2*)(out + (size_t)n * D + f) = make_float2(a0, a1);
        } else {
            float a0 = 0.f;
            int e = s0;
            for (; e + 1 < s1; e += 2) {
                const int2 p0 = epack[e];
                const int2 p1 = epack[e + 1];
                float h0 = H[(size_t)p0.x * D + f];
                float h1 = H[(size_t)p1.x * D + f];
                a0 = fmaf(__int_as_float(p0.y), h0, a0);
                a0 = fmaf(__int_as_float(p1.y), h1, a0);
            }
            if (e < s1) {
                const int2 p0 = epack[e];
                a0 = fmaf(__int_as_float(p0.y), H[(size_t)p0.x * D + f], a0);
            }
            a0 = fmaxf(fmaf(invdeg[n], H[(size_t)n * D + f], a0) + bias[f], 0.f);
            out[(size_t)n * D + f] = a0;
        }
    } else {  // D == 32
        const int sub = lane >> 5;
        const int f = lane & 31;
        const int n = wid * 2 + sub;
        if (n >= nNodes) return;
        float a0 = 0.f;
        const int s0 = rowptr[n], s1 = rowptr[n + 1];
        int e = s0;
        for (; e + 1 < s1; e += 2) {
            const int2 p0 = epack[e];
            const int2 p1 = epack[e + 1];
            float h0 = H[(size_t)p0.x * D + f];
            float h1 = H[(size_t)p1.x * D + f];
            a0 = fmaf(__int_as_float(p0.y), h0, a0);
            a0 = fmaf(__int_as_float(p1.y), h1, a0);
        }
        if (e < s1) {
            const int2 p0 = epack[e];
            a0 = fmaf(__int_as_float(p0.y), H[(size_t)p0.x * D + f], a0);
        }
        a0 = fmaxf(fmaf(invdeg[n], H[(size_t)n * D + f], a0) + bias[f], 0.f);
        out[(size_t)n * D + f] = a0;
    }
}

// ---------------------------------------------------------------------------
// Pool: batch is SORTED -> one block per graph, binary search the range.
__global__ __launch_bounds__(256) void pool2_kernel(const float* __restrict__ h,
                                                    const int* __restrict__ batch,
                                                    float* __restrict__ pooled, int n) {
    const int g = blockIdx.x;
    int lo = 0, hi = n;
    while (lo < hi) { int m = (lo + hi) >> 1; if (batch[m] < g) lo = m + 1; else hi = m; }
    const int start = lo;
    lo = start; hi = n;
    while (lo < hi) { int m = (lo + hi) >> 1; if (batch[m] < g + 1) lo = m + 1; else hi = m; }
    const int end = lo;

    __shared__ float part[256];
    const int f = threadIdx.x & 31;
    const int r = threadIdx.x >> 5;  // 0..7
    float acc = 0.f;
    for (int i = start + r; i < end; i += 8) acc += h[(size_t)i * 32 + f];
    part[threadIdx.x] = acc;
    __syncthreads();
    if (threadIdx.x < 32) {
        float s = 0.f;
#pragma unroll
        for (int q = 0; q < 8; ++q) s += part[q * 32 + f];
        float inv = 1.0f / fmaxf((float)(end - start), 1.0f);
        pooled[g * 32 + f] = s * inv;
    }
}

__global__ void final_kernel(const float* __restrict__ pooled,
                             const float* __restrict__ Wl, const float* __restrict__ bl,
                             float* __restrict__ out) {
    int idx = blockIdx.x * blockDim.x + threadIdx.x;  // [0, 64*768)
    int g = idx / OUTD, o = idx - g * OUTD;
    float acc = bl[o];
#pragma unroll
    for (int k = 0; k < 32; ++k)
        acc = fmaf(pooled[g * 32 + k], Wl[k * OUTD + o], acc);
    out[idx] = acc;
}

// ---------------------------------------------------------------------------
extern "C" void kernel_launch(void* const* d_in, const int* in_sizes, int n_in,
                              void* d_out, int out_size, void* d_ws, size_t ws_size,
                              hipStream_t stream) {
    const float* x = (const float*)d_in[0];
    const int* eidx = (const int*)d_in[1];
    const float* ea = (const float*)d_in[2];
    const int* batch = (const int*)d_in[3];
    const float* W1 = (const float*)d_in[4];
    const float* b1 = (const float*)d_in[5];
    const float* W2 = (const float*)d_in[6];
    const float* b2 = (const float*)d_in[7];
    const float* W3 = (const float*)d_in[8];
    const float* b3 = (const float*)d_in[9];
    const float* Wl = (const float*)d_in[10];
    const float* bl = (const float*)d_in[11];
    const int* src = eidx;
    const int* dst = eidx + NE;

    char* p = (char*)d_ws;
    auto take = [&](size_t bytes) {
        char* r = p;
        p += (bytes + 255) & ~(size_t)255;
        return r;
    };
    float* dinv = (float*)take(NN * 4);
    float* invdeg = (float*)take(NN * 4);
    int* hist = (int*)take(NN * 4);
    int* rowptr = (int*)take((NN + 1) * 4);
    int* blocksum = (int*)take(256 * 4);
    int* blockoff = (int*)take(256 * 4);
    int2* epack = (int2*)take((size_t)NE * 8);
    float* pooled = (float*)take(NG * 32 * 4);
    unsigned int* wmax = (unsigned int*)take(4);
    float* bufA = (float*)take((size_t)NN * 128 * 4);
    float* bufB = (float*)take((size_t)NN * 128 * 4);
    // rank & pcnt alias bufB: both fully consumed by scat_kernel, which
    // completes before agg1 writes bufB (stream-ordered).
    int* rank = (int*)bufB;                                        // 3.2 MB
    unsigned short* pcnt = (unsigned short*)((char*)bufB + (size_t)NE * 4 + 256);  // 6.4 MB

    const int nblk = (NN + 255) / 256;   // 196
    const int eblk = (NE + 255) / 256;   // 3125

    hipMemsetAsync(wmax, 0, 4, stream);

    constexpr int LDS1 = gemm_lds_bytes<128, 64>();   // 66048 (>= 50 KB HR need)
    // gemm1 || max || hist-rank — mutually independent, co-scheduled
    fused1_kernel<<<G1B + MAXB + HRB, 256, LDS1, stream>>>(x, W1, bufA, ea, wmax,
                                                           dst, rank, pcnt);
    comb_kernel<<<nblk, 256, 0, stream>>>(pcnt, hist);
    scan1_kernel<<<nblk, 256, 0, stream>>>(hist, blocksum, NN);
    scan2_kernel<<<1, 256, 0, stream>>>(blocksum, blockoff, &rowptr[NN], nblk);
    scan3_kernel<<<nblk, 256, 0, stream>>>(hist, blockoff, rowptr, NN);
    scat_kernel<<<eblk, 256, 0, stream>>>(src, dst, ea, rowptr, pcnt, rank, epack, NE);
    deg_kernel<<<nblk, 256, 0, stream>>>(epack, rowptr, wmax, dinv, invdeg, NN);
    coef_kernel<<<nblk, 256, 0, stream>>>(epack, rowptr, dinv, wmax, NN);

    // layer 1 aggregate (gemm1 already done inside fused1)
    agg_kernel<128><<<(NN + 3) / 4, 256, 0, stream>>>(bufA, rowptr, epack, invdeg, b1, bufB, NN);
    // layer 2: 128->64
    gemm_kernel<128, 64, 64>
        <<<dim3((NN + 63) / 64, 1), 256, gemm_lds_bytes<128, 64>(), stream>>>(bufB, W2, bufA, NN);
    agg_kernel<64><<<(NN + 3) / 4, 256, 0, stream>>>(bufA, rowptr, epack, invdeg, b2, bufB, NN);
    // layer 3: 64->32
    gemm_kernel<64, 32, 32>
        <<<dim3((NN + 127) / 128, 1), 256, gemm_lds_bytes<64, 32>(), stream>>>(bufB, W3, bufA, NN);
    agg_kernel<32><<<(NN + 7) / 8, 256, 0, stream>>>(bufA, rowptr, epack, invdeg, b3, bufB, NN);

    pool2_kernel<<<NG, 256, 0, stream>>>(bufB, batch, pooled, NN);
    final_kernel<<<(NG * OUTD) / 256, 256, 0, stream>>>(pooled, Wl, bl, (float*)d_out);
}

// Round 6
// 365.917 us; speedup vs baseline: 3.1738x; 1.0433x over previous
//
#include <hip/hip_runtime.h>
#include <hip/hip_bf16.h>

// Problem constants (fixed by the reference)
#define NN 50000
#define NE 800000
#define NG 64
#define OUTD 768

// fused1 block-range dispatch: [gemm1 | max | hist-rank]
#define G1X ((NN + 63) / 64)        // 782
#define G1Y 2
#define G1B (G1X * G1Y)             // 1564 gemm1 blocks
#define MAXB 128                    // max-reduce blocks
#define SSEG 64                     // edge segments
#define TTL 4                       // node tiles
#define ESEG (NE / SSEG)            // 12500 edges / segment
#define NTL (NN / TTL)              // 12500 nodes / tile
#define HRB (SSEG * TTL)            // 256 hist-rank blocks

// ---------------------------------------------------------------------------
// GEMM body: Y[N,D-slice] = X[N,K] @ W[K,D], fp32 vector ALU, LDS tiled,
// 4 rows x 4 cols per thread. LDS is caller-provided (dynamic).
template <int K, int DT>
constexpr int gemm_lds_bytes() {
    constexpr int CG = DT / 4;
    constexpr int RT = 1024 / CG;
    constexpr int KG = K / 4;
    constexpr int XS = RT + 1;
    return KG * XS * 16 + K * DT * 4;
}

template <int K, int D, int DT>
__device__ __forceinline__ void gemm_body(char* smem,
                                          const float* __restrict__ X,
                                          const float* __restrict__ W,
                                          float* __restrict__ Y, int nRows,
                                          int bx, int by) {
    constexpr int CG = DT / 4;       // col groups
    constexpr int RT = 1024 / CG;    // rows per block
    constexpr int KG = K / 4;        // k groups
    constexpr int XS = RT + 1;       // padded stride breaks bank clash
    float4* XsT4 = (float4*)smem;
    float* Ws = (float*)(smem + KG * XS * 16);

    const int tid = threadIdx.x;
    const int rowbase = bx * RT;
    const int cbase = by * DT;

    for (int q = tid; q < K * DT / 4; q += 256) {
        int kw = q / CG;
        int c0 = (q - kw * CG) * 4;
        *(float4*)&Ws[kw * DT + c0] = *(const float4*)&W[kw * D + cbase + c0];
    }
    for (int q = tid; q < RT * KG; q += 256) {
        int r = q / KG;
        int kg = q - r * KG;
        int grow = rowbase + r;
        float4 xv = make_float4(0.f, 0.f, 0.f, 0.f);
        if (grow < nRows) xv = *(const float4*)&X[(size_t)grow * K + kg * 4];
        XsT4[kg * XS + r] = xv;
    }
    __syncthreads();

    const int c0 = (tid % CG) * 4;
    const int r0 = (tid / CG) * 4;
    float acc[4][4] = {};
#pragma unroll 4
    for (int kg = 0; kg < KG; ++kg) {
        float4 xr[4], wk[4];
#pragma unroll
        for (int i = 0; i < 4; ++i) xr[i] = XsT4[kg * XS + r0 + i];
#pragma unroll
        for (int m = 0; m < 4; ++m) wk[m] = *(const float4*)&Ws[(kg * 4 + m) * DT + c0];
#pragma unroll
        for (int i = 0; i < 4; ++i) {
            float xi[4] = {xr[i].x, xr[i].y, xr[i].z, xr[i].w};
#pragma unroll
            for (int m = 0; m < 4; ++m) {
                acc[i][0] = fmaf(xi[m], wk[m].x, acc[i][0]);
                acc[i][1] = fmaf(xi[m], wk[m].y, acc[i][1]);
                acc[i][2] = fmaf(xi[m], wk[m].z, acc[i][2]);
                acc[i][3] = fmaf(xi[m], wk[m].w, acc[i][3]);
            }
        }
    }
#pragma unroll
    for (int i = 0; i < 4; ++i) {
        int grow = rowbase + r0 + i;
        if (grow < nRows)
            *(float4*)&Y[(size_t)grow * D + cbase + c0] =
                make_float4(acc[i][0], acc[i][1], acc[i][2], acc[i][3]);
    }
}

template <int K, int D, int DT>
__global__ __launch_bounds__(256) void gemm_kernel(const float* __restrict__ X,
                                                   const float* __restrict__ W,
                                                   float* __restrict__ Y, int nRows) {
    extern __shared__ char smem[];
    gemm_body<K, D, DT>(smem, X, W, Y, nRows, blockIdx.x, blockIdx.y);
}

// ---------------------------------------------------------------------------
// fused1: [0,G1B) gemm1 (x@W1); [G1B,G1B+MAXB) max(edge_attr);
// rest: hist-rank counting via LDS (NO global atomics).
__global__ __launch_bounds__(256) void fused1_kernel(const float* __restrict__ x,
                                                     const float* __restrict__ W1,
                                                     float* __restrict__ bufA,
                                                     const float* __restrict__ ea,
                                                     unsigned int* wmax,
                                                     const int* __restrict__ dst,
                                                     int* __restrict__ rank,
                                                     unsigned short* __restrict__ pcnt) {
    extern __shared__ char smem[];
    const int b = blockIdx.x;
    if (b < G1B) {
        gemm_body<128, 128, 64>(smem, x, W1, bufA, NN, b % G1X, b / G1X);
    } else if (b < G1B + MAXB) {
        float* red = (float*)smem;
        const int bb = b - G1B;
        float m = 0.0f;
        for (int i = bb * 256 + threadIdx.x; i < NE; i += MAXB * 256)
            m = fmaxf(m, ea[i]);
        red[threadIdx.x] = m;
        __syncthreads();
        for (int off = 128; off > 0; off >>= 1) {
            if (threadIdx.x < off)
                red[threadIdx.x] = fmaxf(red[threadIdx.x], red[threadIdx.x + off]);
            __syncthreads();
        }
        if (threadIdx.x == 0) atomicMax(wmax, __float_as_uint(red[0]));
    } else {
        const int b2 = b - G1B - MAXB;   // 0..HRB-1
        const int seg = b2 >> 2;         // TTL == 4
        const int tile = b2 & 3;
        int* lcnt = (int*)smem;          // NTL ints = 50 KB (< gemm's 66 KB)
        for (int i = threadIdx.x; i < NTL; i += 256) lcnt[i] = 0;
        __syncthreads();
        const int base = seg * ESEG;
        const int nlo = tile * NTL;
        for (int e = base + threadIdx.x; e < base + ESEG; e += 256) {
            int d = dst[e] - nlo;
            if ((unsigned)d < (unsigned)NTL)
                rank[e] = atomicAdd(&lcnt[d], 1);   // LDS atomic
        }
        __syncthreads();
        unsigned short* prow = pcnt + (size_t)seg * NN + nlo;
        for (int i = threadIdx.x; i < NTL; i += 256)
            prow[i] = (unsigned short)lcnt[i];
    }
}

// Per-node: exclusive prefix over segments (in place, u16), total -> hist,
// and fused block-reduction of totals -> blocksum (was scan1).
__global__ __launch_bounds__(256) void comb_kernel(unsigned short* __restrict__ pcnt,
                                                   int* __restrict__ hist,
                                                   int* __restrict__ blocksum) {
    __shared__ int red[256];
    int n = blockIdx.x * 256 + threadIdx.x;
    int run = 0;
    if (n < NN) {
#pragma unroll
        for (int s = 0; s < SSEG; ++s) {
            size_t idx = (size_t)s * NN + n;
            int v = pcnt[idx];
            pcnt[idx] = (unsigned short)run;
            run += v;
        }
        hist[n] = run;
    }
    red[threadIdx.x] = (n < NN) ? run : 0;
    __syncthreads();
    for (int off = 128; off > 0; off >>= 1) {
        if (threadIdx.x < off) red[threadIdx.x] += red[threadIdx.x + off];
        __syncthreads();
    }
    if (threadIdx.x == 0) blocksum[blockIdx.x] = red[0];
}

__global__ __launch_bounds__(256) void scan2_kernel(const int* __restrict__ blocksum,
                                                    int* __restrict__ blockoff,
                                                    int* __restrict__ total_out, int nb) {
    __shared__ int s[256];
    const int tid = threadIdx.x;
    int v = (tid < nb) ? blocksum[tid] : 0;
    s[tid] = v;
    __syncthreads();
    for (int off = 1; off < 256; off <<= 1) {
        int t = (tid >= off) ? s[tid - off] : 0;
        __syncthreads();
        s[tid] += t;
        __syncthreads();
    }
    if (tid < nb) blockoff[tid] = s[tid] - v;
    if (tid == nb - 1) *total_out = s[tid];
}

__global__ __launch_bounds__(256) void scan3_kernel(const int* __restrict__ hist,
                                                    const int* __restrict__ blockoff,
                                                    int* __restrict__ rowptr, int n) {
    __shared__ int s[256];
    const int tid = threadIdx.x;
    int i = blockIdx.x * 256 + tid;
    int v = (i < n) ? hist[i] : 0;
    s[tid] = v;
    __syncthreads();
    for (int off = 1; off < 256; off <<= 1) {
        int t = (tid >= off) ? s[tid - off] : 0;
        __syncthreads();
        s[tid] += t;
        __syncthreads();
    }
    if (i < n) rowptr[i] = blockoff[blockIdx.x] + s[tid] - v;
}

// ---------------------------------------------------------------------------
// Atomic-free scatter: pos = rowptr[d] + pcnt[seg][d] + rank[e].
__global__ void scat_kernel(const int* __restrict__ src, const int* __restrict__ dst,
                            const float* __restrict__ ea,
                            const int* __restrict__ rowptr,
                            const unsigned short* __restrict__ pcnt,
                            const int* __restrict__ rank,
                            int2* __restrict__ epack, int nE) {
    int e = blockIdx.x * blockDim.x + threadIdx.x;
    if (e >= nE) return;
    int s = e / ESEG;
    int d = dst[e];
    int pos = rowptr[d] + (int)pcnt[(size_t)s * NN + d] + rank[e];
    epack[pos] = make_int2(src[e], __float_as_int(ea[e]));
}

// deg from contiguous CSR segments (no atomics): deg = 1 + rw * sum(ea)
__global__ void deg_kernel(const int2* __restrict__ epack, const int* __restrict__ rowptr,
                           const unsigned int* __restrict__ wmax,
                           float* __restrict__ dinv, float* __restrict__ invdeg, int n) {
    int i = blockIdx.x * blockDim.x + threadIdx.x;
    if (i >= n) return;
    float rw = 1.0f / __uint_as_float(*wmax);
    int s0 = rowptr[i], s1 = rowptr[i + 1];
    float s = 0.f;
    for (int e = s0; e < s1; ++e) s += __int_as_float(epack[e].y);
    float d = fmaf(s, rw, 1.0f);
    dinv[i] = rsqrtf(d);
    invdeg[i] = 1.0f / d;
}

// rewrite epack.y: raw ea -> layer-invariant coefficient
__global__ void coef_kernel(int2* __restrict__ epack, const int* __restrict__ rowptr,
                            const float* __restrict__ dinv,
                            const unsigned int* __restrict__ wmax, int n) {
    int i = blockIdx.x * blockDim.x + threadIdx.x;
    if (i >= n) return;
    float rw = 1.0f / __uint_as_float(*wmax);
    float di = dinv[i];
    int s0 = rowptr[i], s1 = rowptr[i + 1];
    for (int e = s0; e < s1; ++e) {
        int2 p = epack[e];
        p.y = __float_as_int(dinv[p.x] * (__int_as_float(p.y) * rw) * di);
        epack[e] = p;
    }
}

// ---------------------------------------------------------------------------
// Aggregation: out[n] = relu( sum_in coef*H[src] + invdeg[n]*H[n] + b )
// One node per wave; wave split into EPW edge-groups of LPE lanes, each lane
// holding a float4 slice (16B/lane). 2x unrolled -> up to 2*EPW edges in
// flight. Cross-group combine via shfl_xor (register-only).
template <int D>
__global__ __launch_bounds__(256) void agg_kernel(const float* __restrict__ H,
                                                  const int* __restrict__ rowptr,
                                                  const int2* __restrict__ epack,
                                                  const float* __restrict__ invdeg,
                                                  const float* __restrict__ bias,
                                                  float* __restrict__ out, int nNodes) {
    constexpr int LPE = D / 4;    // lanes per edge (32 / 16 / 8)
    constexpr int EPW = 64 / LPE; // edges per iter  (2 / 4 / 8)
    const int lane = threadIdx.x & 63;
    const int n = (blockIdx.x << 2) | (threadIdx.x >> 6);
    if (n >= nNodes) return;
    const int esub = lane / LPE;
    const int f4 = (lane % LPE) * 4;
    const int s0 = rowptr[n];
    const int cnt = rowptr[n + 1] - s0;

    float4 acc = make_float4(0.f, 0.f, 0.f, 0.f);
    int kb = 0;
    for (; kb + 2 * EPW <= cnt; kb += 2 * EPW) {
        const int2 pa = epack[s0 + kb + esub];
        const int2 pb = epack[s0 + kb + EPW + esub];
        const float4 ha = *(const float4*)(H + (size_t)pa.x * D + f4);
        const float4 hb = *(const float4*)(H + (size_t)pb.x * D + f4);
        const float ca = __int_as_float(pa.y);
        const float cb = __int_as_float(pb.y);
        acc.x = fmaf(ca, ha.x, acc.x);
        acc.y = fmaf(ca, ha.y, acc.y);
        acc.z = fmaf(ca, ha.z, acc.z);
        acc.w = fmaf(ca, ha.w, acc.w);
        acc.x = fmaf(cb, hb.x, acc.x);
        acc.y = fmaf(cb, hb.y, acc.y);
        acc.z = fmaf(cb, hb.z, acc.z);
        acc.w = fmaf(cb, hb.w, acc.w);
    }
    for (; kb < cnt; kb += EPW) {   // <= 2 guarded tail iterations
        const int idx = kb + esub;
        const bool ok = idx < cnt;
        const int2 p = ok ? epack[s0 + idx] : make_int2(n, 0);
        const float4 h = *(const float4*)(H + (size_t)p.x * D + f4);
        const float c = ok ? __int_as_float(p.y) : 0.f;
        acc.x = fmaf(c, h.x, acc.x);
        acc.y = fmaf(c, h.y, acc.y);
        acc.z = fmaf(c, h.z, acc.z);
        acc.w = fmaf(c, h.w, acc.w);
    }
#pragma unroll
    for (int off = LPE; off < 64; off <<= 1) {
        acc.x += __shfl_xor(acc.x, off);
        acc.y += __shfl_xor(acc.y, off);
        acc.z += __shfl_xor(acc.z, off);
        acc.w += __shfl_xor(acc.w, off);
    }
    if (esub == 0) {
        const float id = invdeg[n];
        const float4 hn = *(const float4*)(H + (size_t)n * D + f4);
        const float4 bv = *(const float4*)(bias + f4);
        float4 o;
        o.x = fmaxf(fmaf(id, hn.x, acc.x) + bv.x, 0.f);
        o.y = fmaxf(fmaf(id, hn.y, acc.y) + bv.y, 0.f);
        o.z = fmaxf(fmaf(id, hn.z, acc.z) + bv.z, 0.f);
        o.w = fmaxf(fmaf(id, hn.w, acc.w) + bv.w, 0.f);
        *(float4*)(out + (size_t)n * D + f4) = o;
    }
}

// ---------------------------------------------------------------------------
// Pool: batch is SORTED -> one block per graph, binary search the range.
__global__ __launch_bounds__(256) void pool2_kernel(const float* __restrict__ h,
                                                    const int* __restrict__ batch,
                                                    float* __restrict__ pooled, int n) {
    const int g = blockIdx.x;
    int lo = 0, hi = n;
    while (lo < hi) { int m = (lo + hi) >> 1; if (batch[m] < g) lo = m + 1; else hi = m; }
    const int start = lo;
    lo = start; hi = n;
    while (lo < hi) { int m = (lo + hi) >> 1; if (batch[m] < g + 1) lo = m + 1; else hi = m; }
    const int end = lo;

    __shared__ float part[256];
    const int f = threadIdx.x & 31;
    const int r = threadIdx.x >> 5;  // 0..7
    float acc = 0.f;
    for (int i = start + r; i < end; i += 8) acc += h[(size_t)i * 32 + f];
    part[threadIdx.x] = acc;
    __syncthreads();
    if (threadIdx.x < 32) {
        float s = 0.f;
#pragma unroll
        for (int q = 0; q < 8; ++q) s += part[q * 32 + f];
        float inv = 1.0f / fmaxf((float)(end - start), 1.0f);
        pooled[g * 32 + f] = s * inv;
    }
}

__global__ void final_kernel(const float* __restrict__ pooled,
                             const float* __restrict__ Wl, const float* __restrict__ bl,
                             float* __restrict__ out) {
    int idx = blockIdx.x * blockDim.x + threadIdx.x;  // [0, 64*768)
    int g = idx / OUTD, o = idx - g * OUTD;
    float acc = bl[o];
#pragma unroll
    for (int k = 0; k < 32; ++k)
        acc = fmaf(pooled[g * 32 + k], Wl[k * OUTD + o], acc);
    out[idx] = acc;
}

// ---------------------------------------------------------------------------
extern "C" void kernel_launch(void* const* d_in, const int* in_sizes, int n_in,
                              void* d_out, int out_size, void* d_ws, size_t ws_size,
                              hipStream_t stream) {
    const float* x = (const float*)d_in[0];
    const int* eidx = (const int*)d_in[1];
    const float* ea = (const float*)d_in[2];
    const int* batch = (const int*)d_in[3];
    const float* W1 = (const float*)d_in[4];
    const float* b1 = (const float*)d_in[5];
    const float* W2 = (const float*)d_in[6];
    const float* b2 = (const float*)d_in[7];
    const float* W3 = (const float*)d_in[8];
    const float* b3 = (const float*)d_in[9];
    const float* Wl = (const float*)d_in[10];
    const float* bl = (const float*)d_in[11];
    const int* src = eidx;
    const int* dst = eidx + NE;

    char* p = (char*)d_ws;
    auto take = [&](size_t bytes) {
        char* r = p;
        p += (bytes + 255) & ~(size_t)255;
        return r;
    };
    float* dinv = (float*)take(NN * 4);
    float* invdeg = (float*)take(NN * 4);
    int* hist = (int*)take(NN * 4);
    int* rowptr = (int*)take((NN + 1) * 4);
    int* blocksum = (int*)take(256 * 4);
    int* blockoff = (int*)take(256 * 4);
    int2* epack = (int2*)take((size_t)NE * 8);
    float* pooled = (float*)take(NG * 32 * 4);
    unsigned int* wmax = (unsigned int*)take(4);
    float* bufA = (float*)take((size_t)NN * 128 * 4);
    float* bufB = (float*)take((size_t)NN * 128 * 4);
    // rank & pcnt alias bufB: both fully consumed by scat_kernel, which
    // completes before agg1 writes bufB (stream-ordered).
    int* rank = (int*)bufB;                                        // 3.2 MB
    unsigned short* pcnt = (unsigned short*)((char*)bufB + (size_t)NE * 4 + 256);  // 6.4 MB

    const int nblk = (NN + 255) / 256;   // 196
    const int eblk = (NE + 255) / 256;   // 3125

    hipMemsetAsync(wmax, 0, 4, stream);

    constexpr int LDS1 = gemm_lds_bytes<128, 64>();   // 66048 (>= 50 KB HR need)
    // gemm1 || max || hist-rank — mutually independent, co-scheduled
    fused1_kernel<<<G1B + MAXB + HRB, 256, LDS1, stream>>>(x, W1, bufA, ea, wmax,
                                                           dst, rank, pcnt);
    comb_kernel<<<nblk, 256, 0, stream>>>(pcnt, hist, blocksum);
    scan2_kernel<<<1, 256, 0, stream>>>(blocksum, blockoff, &rowptr[NN], nblk);
    scan3_kernel<<<nblk, 256, 0, stream>>>(hist, blockoff, rowptr, NN);
    scat_kernel<<<eblk, 256, 0, stream>>>(src, dst, ea, rowptr, pcnt, rank, epack, NE);
    deg_kernel<<<nblk, 256, 0, stream>>>(epack, rowptr, wmax, dinv, invdeg, NN);
    coef_kernel<<<nblk, 256, 0, stream>>>(epack, rowptr, dinv, wmax, NN);

    // layer 1 aggregate (gemm1 already done inside fused1)
    agg_kernel<128><<<(NN + 3) / 4, 256, 0, stream>>>(bufA, rowptr, epack, invdeg, b1, bufB, NN);
    // layer 2: 128->64
    gemm_kernel<128, 64, 64>
        <<<dim3((NN + 63) / 64, 1), 256, gemm_lds_bytes<128, 64>(), stream>>>(bufB, W2, bufA, NN);
    agg_kernel<64><<<(NN + 3) / 4, 256, 0, stream>>>(bufA, rowptr, epack, invdeg, b2, bufB, NN);
    // layer 3: 64->32
    gemm_kernel<64, 32, 32>
        <<<dim3((NN + 127) / 128, 1), 256, gemm_lds_bytes<64, 32>(), stream>>>(bufB, W3, bufA, NN);
    agg_kernel<32><<<(NN + 7) / 8 * 2, 256, 0, stream>>>(bufA, rowptr, epack, invdeg, b3, bufB, NN);

    pool2_kernel<<<NG, 256, 0, stream>>>(bufB, batch, pooled, NN);
    final_kernel<<<(NG * OUTD) / 256, 256, 0, stream>>>(pooled, Wl, bl, (float*)d_out);
}

// Round 7
// 353.477 us; speedup vs baseline: 3.2855x; 1.0352x over previous
//
#include <hip/hip_runtime.h>
#include <hip/hip_bf16.h>

// Problem constants (fixed by the reference)
#define NN 50000
#define NE 800000
#define NG 64
#define OUTD 768

// fused1 block-range dispatch: [gemm1 | max | hist-rank]
#define G1X ((NN + 63) / 64)        // 782
#define G1Y 2
#define G1B (G1X * G1Y)             // 1564 gemm1 blocks
#define MAXB 128                    // max-reduce blocks
#define SSEG 64                     // edge segments
#define TTL 8                       // node tiles (25 KB LDS counters)
#define ESEG (NE / SSEG)            // 12500 edges / segment
#define NTL (NN / TTL)              // 6250 nodes / tile
#define HRB (SSEG * TTL)            // 512 hist-rank blocks

// ---------------------------------------------------------------------------
// GEMM body: Y[N,D-slice] = X[N,K] @ W[K,D], fp32 vector ALU, K-chunked LDS
// tiling (KC k-values per pass -> half the LDS of monolithic staging).
// 4 rows x 4 cols per thread. LDS is caller-provided (dynamic).
template <int DT, int KC>
constexpr int gemm_lds_bytes() {
    constexpr int CG = DT / 4;
    constexpr int RT = 1024 / CG;
    constexpr int KG = KC / 4;
    constexpr int XS = RT + 1;
    return KG * XS * 16 + KC * DT * 4;
}

template <int K, int D, int DT, int KC>
__device__ __forceinline__ void gemm_body(char* smem,
                                          const float* __restrict__ X,
                                          const float* __restrict__ W,
                                          float* __restrict__ Y, int nRows,
                                          int bx, int by) {
    constexpr int CG = DT / 4;       // col groups
    constexpr int RT = 1024 / CG;    // rows per block
    constexpr int KG = KC / 4;       // k groups per chunk
    constexpr int XS = RT + 1;       // padded stride breaks bank clash
    float4* XsT4 = (float4*)smem;
    float* Ws = (float*)(smem + KG * XS * 16);

    const int tid = threadIdx.x;
    const int rowbase = bx * RT;
    const int cbase = by * DT;
    const int c0 = (tid % CG) * 4;
    const int r0 = (tid / CG) * 4;
    float acc[4][4] = {};

    for (int kc = 0; kc < K; kc += KC) {
        if (kc) __syncthreads();     // protect LDS reuse across chunks
        for (int q = tid; q < KC * DT / 4; q += 256) {
            int kw = q / CG;
            int cc = (q - kw * CG) * 4;
            *(float4*)&Ws[kw * DT + cc] = *(const float4*)&W[(kc + kw) * D + cbase + cc];
        }
        for (int q = tid; q < RT * KG; q += 256) {
            int r = q / KG;
            int kg = q - r * KG;
            int grow = rowbase + r;
            float4 xv = make_float4(0.f, 0.f, 0.f, 0.f);
            if (grow < nRows) xv = *(const float4*)&X[(size_t)grow * K + kc + kg * 4];
            XsT4[kg * XS + r] = xv;
        }
        __syncthreads();

#pragma unroll 4
        for (int kg = 0; kg < KG; ++kg) {
            float4 xr[4], wk[4];
#pragma unroll
            for (int i = 0; i < 4; ++i) xr[i] = XsT4[kg * XS + r0 + i];
#pragma unroll
            for (int m = 0; m < 4; ++m) wk[m] = *(const float4*)&Ws[(kg * 4 + m) * DT + c0];
#pragma unroll
            for (int i = 0; i < 4; ++i) {
                float xi[4] = {xr[i].x, xr[i].y, xr[i].z, xr[i].w};
#pragma unroll
                for (int m = 0; m < 4; ++m) {
                    acc[i][0] = fmaf(xi[m], wk[m].x, acc[i][0]);
                    acc[i][1] = fmaf(xi[m], wk[m].y, acc[i][1]);
                    acc[i][2] = fmaf(xi[m], wk[m].z, acc[i][2]);
                    acc[i][3] = fmaf(xi[m], wk[m].w, acc[i][3]);
                }
            }
        }
    }
#pragma unroll
    for (int i = 0; i < 4; ++i) {
        int grow = rowbase + r0 + i;
        if (grow < nRows)
            *(float4*)&Y[(size_t)grow * D + cbase + c0] =
                make_float4(acc[i][0], acc[i][1], acc[i][2], acc[i][3]);
    }
}

template <int K, int D, int DT, int KC>
__global__ __launch_bounds__(256) void gemm_kernel(const float* __restrict__ X,
                                                   const float* __restrict__ W,
                                                   float* __restrict__ Y, int nRows) {
    extern __shared__ char smem[];
    gemm_body<K, D, DT, KC>(smem, X, W, Y, nRows, blockIdx.x, blockIdx.y);
}

// ---------------------------------------------------------------------------
// fused1: [0,G1B) gemm1 (x@W1); [G1B,G1B+MAXB) max(edge_attr);
// rest: hist-rank counting via LDS (NO global atomics).
__global__ __launch_bounds__(256) void fused1_kernel(const float* __restrict__ x,
                                                     const float* __restrict__ W1,
                                                     float* __restrict__ bufA,
                                                     const float* __restrict__ ea,
                                                     unsigned int* wmax,
                                                     const int* __restrict__ dst,
                                                     int* __restrict__ rank,
                                                     unsigned short* __restrict__ pcnt) {
    extern __shared__ char smem[];
    const int b = blockIdx.x;
    if (b < G1B) {
        gemm_body<128, 128, 64, 64>(smem, x, W1, bufA, NN, b % G1X, b / G1X);
    } else if (b < G1B + MAXB) {
        float* red = (float*)smem;
        const int bb = b - G1B;
        float m = 0.0f;
        for (int i = bb * 256 + threadIdx.x; i < NE; i += MAXB * 256)
            m = fmaxf(m, ea[i]);
        red[threadIdx.x] = m;
        __syncthreads();
        for (int off = 128; off > 0; off >>= 1) {
            if (threadIdx.x < off)
                red[threadIdx.x] = fmaxf(red[threadIdx.x], red[threadIdx.x + off]);
            __syncthreads();
        }
        if (threadIdx.x == 0) atomicMax(wmax, __float_as_uint(red[0]));
    } else {
        const int b2 = b - G1B - MAXB;   // 0..HRB-1
        const int seg = b2 >> 3;         // TTL == 8
        const int tile = b2 & 7;
        int* lcnt = (int*)smem;          // NTL ints = 25 KB
        for (int i = threadIdx.x; i < NTL; i += 256) lcnt[i] = 0;
        __syncthreads();
        const int base = seg * ESEG;
        const int nlo = tile * NTL;
        for (int e = base + threadIdx.x; e < base + ESEG; e += 256) {
            int d = dst[e] - nlo;
            if ((unsigned)d < (unsigned)NTL)
                rank[e] = atomicAdd(&lcnt[d], 1);   // LDS atomic
        }
        __syncthreads();
        unsigned short* prow = pcnt + (size_t)seg * NN + nlo;
        for (int i = threadIdx.x; i < NTL; i += 256)
            prow[i] = (unsigned short)lcnt[i];
    }
}

// Per-node: exclusive prefix over segments (in place, u16), total -> hist,
// and fused block-reduction of totals -> blocksum.
__global__ __launch_bounds__(256) void comb_kernel(unsigned short* __restrict__ pcnt,
                                                   int* __restrict__ hist,
                                                   int* __restrict__ blocksum) {
    __shared__ int red[256];
    int n = blockIdx.x * 256 + threadIdx.x;
    int run = 0;
    if (n < NN) {
#pragma unroll
        for (int s = 0; s < SSEG; ++s) {
            size_t idx = (size_t)s * NN + n;
            int v = pcnt[idx];
            pcnt[idx] = (unsigned short)run;
            run += v;
        }
        hist[n] = run;
    }
    red[threadIdx.x] = (n < NN) ? run : 0;
    __syncthreads();
    for (int off = 128; off > 0; off >>= 1) {
        if (threadIdx.x < off) red[threadIdx.x] += red[threadIdx.x + off];
        __syncthreads();
    }
    if (threadIdx.x == 0) blocksum[blockIdx.x] = red[0];
}

__global__ __launch_bounds__(256) void scan2_kernel(const int* __restrict__ blocksum,
                                                    int* __restrict__ blockoff,
                                                    int* __restrict__ total_out, int nb) {
    __shared__ int s[256];
    const int tid = threadIdx.x;
    int v = (tid < nb) ? blocksum[tid] : 0;
    s[tid] = v;
    __syncthreads();
    for (int off = 1; off < 256; off <<= 1) {
        int t = (tid >= off) ? s[tid - off] : 0;
        __syncthreads();
        s[tid] += t;
        __syncthreads();
    }
    if (tid < nb) blockoff[tid] = s[tid] - v;
    if (tid == nb - 1) *total_out = s[tid];
}

__global__ __launch_bounds__(256) void scan3_kernel(const int* __restrict__ hist,
                                                    const int* __restrict__ blockoff,
                                                    int* __restrict__ rowptr, int n) {
    __shared__ int s[256];
    const int tid = threadIdx.x;
    int i = blockIdx.x * 256 + tid;
    int v = (i < n) ? hist[i] : 0;
    s[tid] = v;
    __syncthreads();
    for (int off = 1; off < 256; off <<= 1) {
        int t = (tid >= off) ? s[tid - off] : 0;
        __syncthreads();
        s[tid] += t;
        __syncthreads();
    }
    if (i < n) rowptr[i] = blockoff[blockIdx.x] + s[tid] - v;
}

// ---------------------------------------------------------------------------
// Atomic-free scatter: pos = rowptr[d] + pcnt[seg][d] + rank[e].
__global__ void scat_kernel(const int* __restrict__ src, const int* __restrict__ dst,
                            const float* __restrict__ ea,
                            const int* __restrict__ rowptr,
                            const unsigned short* __restrict__ pcnt,
                            const int* __restrict__ rank,
                            int2* __restrict__ epack, int nE) {
    int e = blockIdx.x * blockDim.x + threadIdx.x;
    if (e >= nE) return;
    int s = e / ESEG;
    int d = dst[e];
    int pos = rowptr[d] + (int)pcnt[(size_t)s * NN + d] + rank[e];
    epack[pos] = make_int2(src[e], __float_as_int(ea[e]));
}

// deg from contiguous CSR segments (no atomics): deg = 1 + rw * sum(ea)
__global__ void deg_kernel(const int2* __restrict__ epack, const int* __restrict__ rowptr,
                           const unsigned int* __restrict__ wmax,
                           float* __restrict__ dinv, float* __restrict__ invdeg, int n) {
    int i = blockIdx.x * blockDim.x + threadIdx.x;
    if (i >= n) return;
    float rw = 1.0f / __uint_as_float(*wmax);
    int s0 = rowptr[i], s1 = rowptr[i + 1];
    float s = 0.f;
    for (int e = s0; e < s1; ++e) s += __int_as_float(epack[e].y);
    float d = fmaf(s, rw, 1.0f);
    dinv[i] = rsqrtf(d);
    invdeg[i] = 1.0f / d;
}

// rewrite epack.y: raw ea -> layer-invariant coefficient
__global__ void coef_kernel(int2* __restrict__ epack, const int* __restrict__ rowptr,
                            const float* __restrict__ dinv,
                            const unsigned int* __restrict__ wmax, int n) {
    int i = blockIdx.x * blockDim.x + threadIdx.x;
    if (i >= n) return;
    float rw = 1.0f / __uint_as_float(*wmax);
    float di = dinv[i];
    int s0 = rowptr[i], s1 = rowptr[i + 1];
    for (int e = s0; e < s1; ++e) {
        int2 p = epack[e];
        p.y = __float_as_int(dinv[p.x] * (__int_as_float(p.y) * rw) * di);
        epack[e] = p;
    }
}

// ---------------------------------------------------------------------------
// Aggregation: out[n] = relu( sum_in coef*H[src] + invdeg[n]*H[n] + b )
// One node per wave; wave split into EPW edge-groups of LPE lanes, each lane
// holding a float4 slice (16B/lane). 2x unrolled. shfl_xor combine.
template <int D>
__global__ __launch_bounds__(256) void agg_kernel(const float* __restrict__ H,
                                                  const int* __restrict__ rowptr,
                                                  const int2* __restrict__ epack,
                                                  const float* __restrict__ invdeg,
                                                  const float* __restrict__ bias,
                                                  float* __restrict__ out, int nNodes) {
    constexpr int LPE = D / 4;    // lanes per edge (32 / 16 / 8)
    constexpr int EPW = 64 / LPE; // edges per iter  (2 / 4 / 8)
    const int lane = threadIdx.x & 63;
    const int n = (blockIdx.x << 2) | (threadIdx.x >> 6);
    if (n >= nNodes) return;
    const int esub = lane / LPE;
    const int f4 = (lane % LPE) * 4;
    const int s0 = rowptr[n];
    const int cnt = rowptr[n + 1] - s0;

    float4 acc = make_float4(0.f, 0.f, 0.f, 0.f);
    int kb = 0;
    for (; kb + 2 * EPW <= cnt; kb += 2 * EPW) {
        const int2 pa = epack[s0 + kb + esub];
        const int2 pb = epack[s0 + kb + EPW + esub];
        const float4 ha = *(const float4*)(H + (size_t)pa.x * D + f4);
        const float4 hb = *(const float4*)(H + (size_t)pb.x * D + f4);
        const float ca = __int_as_float(pa.y);
        const float cb = __int_as_float(pb.y);
        acc.x = fmaf(ca, ha.x, acc.x);
        acc.y = fmaf(ca, ha.y, acc.y);
        acc.z = fmaf(ca, ha.z, acc.z);
        acc.w = fmaf(ca, ha.w, acc.w);
        acc.x = fmaf(cb, hb.x, acc.x);
        acc.y = fmaf(cb, hb.y, acc.y);
        acc.z = fmaf(cb, hb.z, acc.z);
        acc.w = fmaf(cb, hb.w, acc.w);
    }
    for (; kb < cnt; kb += EPW) {   // <= 2 guarded tail iterations
        const int idx = kb + esub;
        const bool ok = idx < cnt;
        const int2 p = ok ? epack[s0 + idx] : make_int2(n, 0);
        const float4 h = *(const float4*)(H + (size_t)p.x * D + f4);
        const float c = ok ? __int_as_float(p.y) : 0.f;
        acc.x = fmaf(c, h.x, acc.x);
        acc.y = fmaf(c, h.y, acc.y);
        acc.z = fmaf(c, h.z, acc.z);
        acc.w = fmaf(c, h.w, acc.w);
    }
#pragma unroll
    for (int off = LPE; off < 64; off <<= 1) {
        acc.x += __shfl_xor(acc.x, off);
        acc.y += __shfl_xor(acc.y, off);
        acc.z += __shfl_xor(acc.z, off);
        acc.w += __shfl_xor(acc.w, off);
    }
    if (esub == 0) {
        const float id = invdeg[n];
        const float4 hn = *(const float4*)(H + (size_t)n * D + f4);
        const float4 bv = *(const float4*)(bias + f4);
        float4 o;
        o.x = fmaxf(fmaf(id, hn.x, acc.x) + bv.x, 0.f);
        o.y = fmaxf(fmaf(id, hn.y, acc.y) + bv.y, 0.f);
        o.z = fmaxf(fmaf(id, hn.z, acc.z) + bv.z, 0.f);
        o.w = fmaxf(fmaf(id, hn.w, acc.w) + bv.w, 0.f);
        *(float4*)(out + (size_t)n * D + f4) = o;
    }
}

// ---------------------------------------------------------------------------
// Pool: batch is SORTED -> one block per graph, binary search the range.
__global__ __launch_bounds__(256) void pool2_kernel(const float* __restrict__ h,
                                                    const int* __restrict__ batch,
                                                    float* __restrict__ pooled, int n) {
    const int g = blockIdx.x;
    int lo = 0, hi = n;
    while (lo < hi) { int m = (lo + hi) >> 1; if (batch[m] < g) lo = m + 1; else hi = m; }
    const int start = lo;
    lo = start; hi = n;
    while (lo < hi) { int m = (lo + hi) >> 1; if (batch[m] < g + 1) lo = m + 1; else hi = m; }
    const int end = lo;

    __shared__ float part[256];
    const int f = threadIdx.x & 31;
    const int r = threadIdx.x >> 5;  // 0..7
    float acc = 0.f;
    for (int i = start + r; i < end; i += 8) acc += h[(size_t)i * 32 + f];
    part[threadIdx.x] = acc;
    __syncthreads();
    if (threadIdx.x < 32) {
        float s = 0.f;
#pragma unroll
        for (int q = 0; q < 8; ++q) s += part[q * 32 + f];
        float inv = 1.0f / fmaxf((float)(end - start), 1.0f);
        pooled[g * 32 + f] = s * inv;
    }
}

__global__ void final_kernel(const float* __restrict__ pooled,
                             const float* __restrict__ Wl, const float* __restrict__ bl,
                             float* __restrict__ out) {
    int idx = blockIdx.x * blockDim.x + threadIdx.x;  // [0, 64*768)
    int g = idx / OUTD, o = idx - g * OUTD;
    float acc = bl[o];
#pragma unroll
    for (int k = 0; k < 32; ++k)
        acc = fmaf(pooled[g * 32 + k], Wl[k * OUTD + o], acc);
    out[idx] = acc;
}

// ---------------------------------------------------------------------------
extern "C" void kernel_launch(void* const* d_in, const int* in_sizes, int n_in,
                              void* d_out, int out_size, void* d_ws, size_t ws_size,
                              hipStream_t stream) {
    const float* x = (const float*)d_in[0];
    const int* eidx = (const int*)d_in[1];
    const float* ea = (const float*)d_in[2];
    const int* batch = (const int*)d_in[3];
    const float* W1 = (const float*)d_in[4];
    const float* b1 = (const float*)d_in[5];
    const float* W2 = (const float*)d_in[6];
    const float* b2 = (const float*)d_in[7];
    const float* W3 = (const float*)d_in[8];
    const float* b3 = (const float*)d_in[9];
    const float* Wl = (const float*)d_in[10];
    const float* bl = (const float*)d_in[11];
    const int* src = eidx;
    const int* dst = eidx + NE;

    char* p = (char*)d_ws;
    auto take = [&](size_t bytes) {
        char* r = p;
        p += (bytes + 255) & ~(size_t)255;
        return r;
    };
    float* dinv = (float*)take(NN * 4);
    float* invdeg = (float*)take(NN * 4);
    int* hist = (int*)take(NN * 4);
    int* rowptr = (int*)take((NN + 1) * 4);
    int* blocksum = (int*)take(256 * 4);
    int* blockoff = (int*)take(256 * 4);
    int2* epack = (int2*)take((size_t)NE * 8);
    float* pooled = (float*)take(NG * 32 * 4);
    unsigned int* wmax = (unsigned int*)take(4);
    float* bufA = (float*)take((size_t)NN * 128 * 4);
    float* bufB = (float*)take((size_t)NN * 128 * 4);
    // rank & pcnt alias bufB: both fully consumed by scat_kernel, which
    // completes before agg1 writes bufB (stream-ordered).
    int* rank = (int*)bufB;                                        // 3.2 MB
    unsigned short* pcnt = (unsigned short*)((char*)bufB + (size_t)NE * 4 + 256);  // 6.4 MB

    const int nblk = (NN + 255) / 256;   // 196
    const int eblk = (NE + 255) / 256;   // 3125

    hipMemsetAsync(wmax, 0, 4, stream);

    constexpr int LDS1 = gemm_lds_bytes<64, 64>();   // 33024 -> 4 blocks/CU
    static_assert(LDS1 >= NTL * 4, "HR branch LDS must fit");
    // gemm1 || max || hist-rank — mutually independent, co-scheduled
    fused1_kernel<<<G1B + MAXB + HRB, 256, LDS1, stream>>>(x, W1, bufA, ea, wmax,
                                                           dst, rank, pcnt);
    comb_kernel<<<nblk, 256, 0, stream>>>(pcnt, hist, blocksum);
    scan2_kernel<<<1, 256, 0, stream>>>(blocksum, blockoff, &rowptr[NN], nblk);
    scan3_kernel<<<nblk, 256, 0, stream>>>(hist, blockoff, rowptr, NN);
    scat_kernel<<<eblk, 256, 0, stream>>>(src, dst, ea, rowptr, pcnt, rank, epack, NE);
    deg_kernel<<<nblk, 256, 0, stream>>>(epack, rowptr, wmax, dinv, invdeg, NN);
    coef_kernel<<<nblk, 256, 0, stream>>>(epack, rowptr, dinv, wmax, NN);

    // layer 1 aggregate (gemm1 already done inside fused1)
    agg_kernel<128><<<(NN + 3) / 4, 256, 0, stream>>>(bufA, rowptr, epack, invdeg, b1, bufB, NN);
    // layer 2: 128->64
    gemm_kernel<128, 64, 64, 64>
        <<<dim3((NN + 63) / 64, 1), 256, gemm_lds_bytes<64, 64>(), stream>>>(bufB, W2, bufA, NN);
    agg_kernel<64><<<(NN + 3) / 4, 256, 0, stream>>>(bufA, rowptr, epack, invdeg, b2, bufB, NN);
    // layer 3: 64->32
    gemm_kernel<64, 32, 32, 32>
        <<<dim3((NN + 127) / 128, 1), 256, gemm_lds_bytes<32, 32>(), stream>>>(bufB, W3, bufA, NN);
    agg_kernel<32><<<(NN + 7) / 8 * 2, 256, 0, stream>>>(bufA, rowptr, epack, invdeg, b3, bufB, NN);

    pool2_kernel<<<NG, 256, 0, stream>>>(bufB, batch, pooled, NN);
    final_kernel<<<(NG * OUTD) / 256, 256, 0, stream>>>(pooled, Wl, bl, (float*)d_out);
}

// Round 8
// 324.463 us; speedup vs baseline: 3.5793x; 1.0894x over previous
//
#include <hip/hip_runtime.h>
#include <hip/hip_bf16.h>

// Problem constants (fixed by the reference)
#define NN 50000
#define NE 800000
#define NG 64
#define OUTD 768

// fused1 block-range dispatch: [gemm1 | max | hist-rank]
#define G1X ((NN + 63) / 64)        // 782
#define G1Y 2
#define G1B (G1X * G1Y)             // 1564 gemm1 blocks
#define MAXB 128                    // max-reduce blocks
#define SSEG 64                     // edge segments
#define TTL 8                       // node tiles (25 KB LDS counters)
#define ESEG (NE / SSEG)            // 12500 edges / segment
#define NTL (NN / TTL)              // 6250 nodes / tile
#define HRB (SSEG * TTL)            // 512 hist-rank blocks

// bf16 helpers: storage is ushort, math is fp32 (RTN-even on store)
__device__ __forceinline__ float bflo(unsigned int u) { return __uint_as_float(u << 16); }
__device__ __forceinline__ float bfhi(unsigned int u) { return __uint_as_float(u & 0xffff0000u); }
__device__ __forceinline__ unsigned short f2bf(float f) {
    unsigned int u = __float_as_uint(f);
    return (unsigned short)((u + 0x7fffu + ((u >> 16) & 1u)) >> 16);
}
__device__ __forceinline__ unsigned int pack2bf(float lo, float hi) {
    return (unsigned int)f2bf(lo) | ((unsigned int)f2bf(hi) << 16);
}

// ---------------------------------------------------------------------------
// GEMM body: Y[N,D-slice](bf16) = X[N,K] @ W[K,D], fp32 math, K-chunked LDS.
// X may be fp32 (layer 1) or bf16 (layers 2/3); unpacked to fp32 during staging.
template <int DT, int KC>
constexpr int gemm_lds_bytes() {
    constexpr int CG = DT / 4;
    constexpr int RT = 1024 / CG;
    constexpr int KG = KC / 4;
    constexpr int XS = RT + 1;
    return KG * XS * 16 + KC * DT * 4;
}

template <int K, int D, int DT, int KC, typename TX>
__device__ __forceinline__ void gemm_body(char* smem,
                                          const TX* __restrict__ X,
                                          const float* __restrict__ W,
                                          unsigned short* __restrict__ Y, int nRows,
                                          int bx, int by) {
    constexpr int CG = DT / 4;       // col groups
    constexpr int RT = 1024 / CG;    // rows per block
    constexpr int KG = KC / 4;       // k groups per chunk
    constexpr int XS = RT + 1;       // padded stride breaks bank clash
    float4* XsT4 = (float4*)smem;
    float* Ws = (float*)(smem + KG * XS * 16);

    const int tid = threadIdx.x;
    const int rowbase = bx * RT;
    const int cbase = by * DT;
    const int c0 = (tid % CG) * 4;
    const int r0 = (tid / CG) * 4;
    float acc[4][4] = {};

    for (int kc = 0; kc < K; kc += KC) {
        if (kc) __syncthreads();     // protect LDS reuse across chunks
        for (int q = tid; q < KC * DT / 4; q += 256) {
            int kw = q / CG;
            int cc = (q - kw * CG) * 4;
            *(float4*)&Ws[kw * DT + cc] = *(const float4*)&W[(kc + kw) * D + cbase + cc];
        }
        for (int q = tid; q < RT * KG; q += 256) {
            int r = q / KG;
            int kg = q - r * KG;
            int grow = rowbase + r;
            float4 xv = make_float4(0.f, 0.f, 0.f, 0.f);
            if (grow < nRows) {
                if constexpr (sizeof(TX) == 4) {
                    xv = *(const float4*)&X[(size_t)grow * K + kc + kg * 4];
                } else {
                    uint2 u = *(const uint2*)&X[(size_t)grow * K + kc + kg * 4];
                    xv = make_float4(bflo(u.x), bfhi(u.x), bflo(u.y), bfhi(u.y));
                }
            }
            XsT4[kg * XS + r] = xv;
        }
        __syncthreads();

#pragma unroll 4
        for (int kg = 0; kg < KG; ++kg) {
            float4 xr[4], wk[4];
#pragma unroll
            for (int i = 0; i < 4; ++i) xr[i] = XsT4[kg * XS + r0 + i];
#pragma unroll
            for (int m = 0; m < 4; ++m) wk[m] = *(const float4*)&Ws[(kg * 4 + m) * DT + c0];
#pragma unroll
            for (int i = 0; i < 4; ++i) {
                float xi[4] = {xr[i].x, xr[i].y, xr[i].z, xr[i].w};
#pragma unroll
                for (int m = 0; m < 4; ++m) {
                    acc[i][0] = fmaf(xi[m], wk[m].x, acc[i][0]);
                    acc[i][1] = fmaf(xi[m], wk[m].y, acc[i][1]);
                    acc[i][2] = fmaf(xi[m], wk[m].z, acc[i][2]);
                    acc[i][3] = fmaf(xi[m], wk[m].w, acc[i][3]);
                }
            }
        }
    }
#pragma unroll
    for (int i = 0; i < 4; ++i) {
        int grow = rowbase + r0 + i;
        if (grow < nRows) {
            uint2 o;
            o.x = pack2bf(acc[i][0], acc[i][1]);
            o.y = pack2bf(acc[i][2], acc[i][3]);
            *(uint2*)&Y[(size_t)grow * D + cbase + c0] = o;
        }
    }
}

template <int K, int D, int DT, int KC, typename TX>
__global__ __launch_bounds__(256) void gemm_kernel(const TX* __restrict__ X,
                                                   const float* __restrict__ W,
                                                   unsigned short* __restrict__ Y,
                                                   int nRows) {
    extern __shared__ char smem[];
    gemm_body<K, D, DT, KC>(smem, X, W, Y, nRows, blockIdx.x, blockIdx.y);
}

// ---------------------------------------------------------------------------
// fused1: [0,G1B) gemm1 (x@W1, fp32 in -> bf16 out); [G1B,G1B+MAXB) max(ea);
// rest: hist-rank counting via LDS (NO global atomics).
__global__ __launch_bounds__(256) void fused1_kernel(const float* __restrict__ x,
                                                     const float* __restrict__ W1,
                                                     unsigned short* __restrict__ bufA,
                                                     const float* __restrict__ ea,
                                                     unsigned int* wmax,
                                                     const int* __restrict__ dst,
                                                     int* __restrict__ rank,
                                                     unsigned short* __restrict__ pcnt) {
    extern __shared__ char smem[];
    const int b = blockIdx.x;
    if (b < G1B) {
        gemm_body<128, 128, 64, 64>(smem, x, W1, bufA, NN, b % G1X, b / G1X);
    } else if (b < G1B + MAXB) {
        float* red = (float*)smem;
        const int bb = b - G1B;
        float m = 0.0f;
        for (int i = bb * 256 + threadIdx.x; i < NE; i += MAXB * 256)
            m = fmaxf(m, ea[i]);
        red[threadIdx.x] = m;
        __syncthreads();
        for (int off = 128; off > 0; off >>= 1) {
            if (threadIdx.x < off)
                red[threadIdx.x] = fmaxf(red[threadIdx.x], red[threadIdx.x + off]);
            __syncthreads();
        }
        if (threadIdx.x == 0) atomicMax(wmax, __float_as_uint(red[0]));
    } else {
        const int b2 = b - G1B - MAXB;   // 0..HRB-1
        const int seg = b2 >> 3;         // TTL == 8
        const int tile = b2 & 7;
        int* lcnt = (int*)smem;          // NTL ints = 25 KB
        for (int i = threadIdx.x; i < NTL; i += 256) lcnt[i] = 0;
        __syncthreads();
        const int base = seg * ESEG;
        const int nlo = tile * NTL;
        for (int e = base + threadIdx.x; e < base + ESEG; e += 256) {
            int d = dst[e] - nlo;
            if ((unsigned)d < (unsigned)NTL)
                rank[e] = atomicAdd(&lcnt[d], 1);   // LDS atomic
        }
        __syncthreads();
        unsigned short* prow = pcnt + (size_t)seg * NN + nlo;
        for (int i = threadIdx.x; i < NTL; i += 256)
            prow[i] = (unsigned short)lcnt[i];
    }
}

// Per-node: exclusive prefix over segments (in place, u16), total -> hist,
// and fused block-reduction of totals -> blocksum.
__global__ __launch_bounds__(256) void comb_kernel(unsigned short* __restrict__ pcnt,
                                                   int* __restrict__ hist,
                                                   int* __restrict__ blocksum) {
    __shared__ int red[256];
    int n = blockIdx.x * 256 + threadIdx.x;
    int run = 0;
    if (n < NN) {
#pragma unroll
        for (int s = 0; s < SSEG; ++s) {
            size_t idx = (size_t)s * NN + n;
            int v = pcnt[idx];
            pcnt[idx] = (unsigned short)run;
            run += v;
        }
        hist[n] = run;
    }
    red[threadIdx.x] = (n < NN) ? run : 0;
    __syncthreads();
    for (int off = 128; off > 0; off >>= 1) {
        if (threadIdx.x < off) red[threadIdx.x] += red[threadIdx.x + off];
        __syncthreads();
    }
    if (threadIdx.x == 0) blocksum[blockIdx.x] = red[0];
}

__global__ __launch_bounds__(256) void scan2_kernel(const int* __restrict__ blocksum,
                                                    int* __restrict__ blockoff,
                                                    int* __restrict__ total_out, int nb) {
    __shared__ int s[256];
    const int tid = threadIdx.x;
    int v = (tid < nb) ? blocksum[tid] : 0;
    s[tid] = v;
    __syncthreads();
    for (int off = 1; off < 256; off <<= 1) {
        int t = (tid >= off) ? s[tid - off] : 0;
        __syncthreads();
        s[tid] += t;
        __syncthreads();
    }
    if (tid < nb) blockoff[tid] = s[tid] - v;
    if (tid == nb - 1) *total_out = s[tid];
}

__global__ __launch_bounds__(256) void scan3_kernel(const int* __restrict__ hist,
                                                    const int* __restrict__ blockoff,
                                                    int* __restrict__ rowptr, int n) {
    __shared__ int s[256];
    const int tid = threadIdx.x;
    int i = blockIdx.x * 256 + tid;
    int v = (i < n) ? hist[i] : 0;
    s[tid] = v;
    __syncthreads();
    for (int off = 1; off < 256; off <<= 1) {
        int t = (tid >= off) ? s[tid - off] : 0;
        __syncthreads();
        s[tid] += t;
        __syncthreads();
    }
    if (i < n) rowptr[i] = blockoff[blockIdx.x] + s[tid] - v;
}

// ---------------------------------------------------------------------------
// Atomic-free scatter: pos = rowptr[d] + pcnt[seg][d] + rank[e].
__global__ void scat_kernel(const int* __restrict__ src, const int* __restrict__ dst,
                            const float* __restrict__ ea,
                            const int* __restrict__ rowptr,
                            const unsigned short* __restrict__ pcnt,
                            const int* __restrict__ rank,
                            int2* __restrict__ epack, int nE) {
    int e = blockIdx.x * blockDim.x + threadIdx.x;
    if (e >= nE) return;
    int s = e / ESEG;
    int d = dst[e];
    int pos = rowptr[d] + (int)pcnt[(size_t)s * NN + d] + rank[e];
    epack[pos] = make_int2(src[e], __float_as_int(ea[e]));
}

// deg from contiguous CSR segments (no atomics): deg = 1 + rw * sum(ea)
__global__ void deg_kernel(const int2* __restrict__ epack, const int* __restrict__ rowptr,
                           const unsigned int* __restrict__ wmax,
                           float* __restrict__ dinv, float* __restrict__ invdeg, int n) {
    int i = blockIdx.x * blockDim.x + threadIdx.x;
    if (i >= n) return;
    float rw = 1.0f / __uint_as_float(*wmax);
    int s0 = rowptr[i], s1 = rowptr[i + 1];
    float s = 0.f;
    for (int e = s0; e < s1; ++e) s += __int_as_float(epack[e].y);
    float d = fmaf(s, rw, 1.0f);
    dinv[i] = rsqrtf(d);
    invdeg[i] = 1.0f / d;
}

// rewrite epack.y: raw ea -> layer-invariant coefficient
__global__ void coef_kernel(int2* __restrict__ epack, const int* __restrict__ rowptr,
                            const float* __restrict__ dinv,
                            const unsigned int* __restrict__ wmax, int n) {
    int i = blockIdx.x * blockDim.x + threadIdx.x;
    if (i >= n) return;
    float rw = 1.0f / __uint_as_float(*wmax);
    float di = dinv[i];
    int s0 = rowptr[i], s1 = rowptr[i + 1];
    for (int e = s0; e < s1; ++e) {
        int2 p = epack[e];
        p.y = __float_as_int(dinv[p.x] * (__int_as_float(p.y) * rw) * di);
        epack[e] = p;
    }
}

// ---------------------------------------------------------------------------
// Aggregation over bf16 H: out = relu( sum coef*H[src] + invdeg[n]*H[n] + b ).
// One node per wave; EPW = 64/(D/8) edges in flight per iter, 16B (8 bf16)
// per lane, fp32 accumulate, shfl_xor combine, bf16 store.
template <int D>
__global__ __launch_bounds__(256) void agg_kernel(const unsigned short* __restrict__ H,
                                                  const int* __restrict__ rowptr,
                                                  const int2* __restrict__ epack,
                                                  const float* __restrict__ invdeg,
                                                  const float* __restrict__ bias,
                                                  unsigned short* __restrict__ out,
                                                  int nNodes) {
    constexpr int LPE = D / 8;    // lanes per edge (16 / 8 / 4)
    constexpr int EPW = 64 / LPE; // edges per iter  (4 / 8 / 16)
    const int lane = threadIdx.x & 63;
    const int n = (blockIdx.x << 2) | (threadIdx.x >> 6);
    if (n >= nNodes) return;
    const int esub = lane / LPE;
    const int f8 = (lane % LPE) * 8;
    const int s0 = rowptr[n];
    const int cnt = rowptr[n + 1] - s0;

    float a[8] = {};
    int kb = 0;
    for (; kb + 2 * EPW <= cnt; kb += 2 * EPW) {
        const int2 pa = epack[s0 + kb + esub];
        const int2 pb = epack[s0 + kb + EPW + esub];
        const uint4 ua = *(const uint4*)(H + (size_t)pa.x * D + f8);
        const uint4 ub = *(const uint4*)(H + (size_t)pb.x * D + f8);
        const float ca = __int_as_float(pa.y);
        const float cb = __int_as_float(pb.y);
        a[0] = fmaf(ca, bflo(ua.x), a[0]); a[1] = fmaf(ca, bfhi(ua.x), a[1]);
        a[2] = fmaf(ca, bflo(ua.y), a[2]); a[3] = fmaf(ca, bfhi(ua.y), a[3]);
        a[4] = fmaf(ca, bflo(ua.z), a[4]); a[5] = fmaf(ca, bfhi(ua.z), a[5]);
        a[6] = fmaf(ca, bflo(ua.w), a[6]); a[7] = fmaf(ca, bfhi(ua.w), a[7]);
        a[0] = fmaf(cb, bflo(ub.x), a[0]); a[1] = fmaf(cb, bfhi(ub.x), a[1]);
        a[2] = fmaf(cb, bflo(ub.y), a[2]); a[3] = fmaf(cb, bfhi(ub.y), a[3]);
        a[4] = fmaf(cb, bflo(ub.z), a[4]); a[5] = fmaf(cb, bfhi(ub.z), a[5]);
        a[6] = fmaf(cb, bflo(ub.w), a[6]); a[7] = fmaf(cb, bfhi(ub.w), a[7]);
    }
    for (; kb < cnt; kb += EPW) {   // <= 2 guarded tail iterations
        const int idx = kb + esub;
        const bool ok = idx < cnt;
        const int2 p = ok ? epack[s0 + idx] : make_int2(n, 0);
        const uint4 u = *(const uint4*)(H + (size_t)p.x * D + f8);
        const float c = ok ? __int_as_float(p.y) : 0.f;
        a[0] = fmaf(c, bflo(u.x), a[0]); a[1] = fmaf(c, bfhi(u.x), a[1]);
        a[2] = fmaf(c, bflo(u.y), a[2]); a[3] = fmaf(c, bfhi(u.y), a[3]);
        a[4] = fmaf(c, bflo(u.z), a[4]); a[5] = fmaf(c, bfhi(u.z), a[5]);
        a[6] = fmaf(c, bflo(u.w), a[6]); a[7] = fmaf(c, bfhi(u.w), a[7]);
    }
#pragma unroll
    for (int off = LPE; off < 64; off <<= 1) {
#pragma unroll
        for (int j = 0; j < 8; ++j) a[j] += __shfl_xor(a[j], off);
    }
    if (esub == 0) {
        const float id = invdeg[n];
        const uint4 un = *(const uint4*)(H + (size_t)n * D + f8);
        const float4 b0 = *(const float4*)(bias + f8);
        const float4 b1 = *(const float4*)(bias + f8 + 4);
        float o[8];
        o[0] = fmaxf(fmaf(id, bflo(un.x), a[0]) + b0.x, 0.f);
        o[1] = fmaxf(fmaf(id, bfhi(un.x), a[1]) + b0.y, 0.f);
        o[2] = fmaxf(fmaf(id, bflo(un.y), a[2]) + b0.z, 0.f);
        o[3] = fmaxf(fmaf(id, bfhi(un.y), a[3]) + b0.w, 0.f);
        o[4] = fmaxf(fmaf(id, bflo(un.z), a[4]) + b1.x, 0.f);
        o[5] = fmaxf(fmaf(id, bfhi(un.z), a[5]) + b1.y, 0.f);
        o[6] = fmaxf(fmaf(id, bflo(un.w), a[6]) + b1.z, 0.f);
        o[7] = fmaxf(fmaf(id, bfhi(un.w), a[7]) + b1.w, 0.f);
        uint4 w;
        w.x = pack2bf(o[0], o[1]);
        w.y = pack2bf(o[2], o[3]);
        w.z = pack2bf(o[4], o[5]);
        w.w = pack2bf(o[6], o[7]);
        *(uint4*)(out + (size_t)n * D + f8) = w;
    }
}

// ---------------------------------------------------------------------------
// Pool (bf16 input): batch SORTED -> one block per graph, binary search range.
__global__ __launch_bounds__(256) void pool2_kernel(const unsigned short* __restrict__ h,
                                                    const int* __restrict__ batch,
                                                    float* __restrict__ pooled, int n) {
    const int g = blockIdx.x;
    int lo = 0, hi = n;
    while (lo < hi) { int m = (lo + hi) >> 1; if (batch[m] < g) lo = m + 1; else hi = m; }
    const int start = lo;
    lo = start; hi = n;
    while (lo < hi) { int m = (lo + hi) >> 1; if (batch[m] < g + 1) lo = m + 1; else hi = m; }
    const int end = lo;

    __shared__ float part[256];
    const int f = threadIdx.x & 31;
    const int r = threadIdx.x >> 5;  // 0..7
    float acc = 0.f;
    for (int i = start + r; i < end; i += 8)
        acc += __uint_as_float((unsigned int)h[(size_t)i * 32 + f] << 16);
    part[threadIdx.x] = acc;
    __syncthreads();
    if (threadIdx.x < 32) {
        float s = 0.f;
#pragma unroll
        for (int q = 0; q < 8; ++q) s += part[q * 32 + f];
        float inv = 1.0f / fmaxf((float)(end - start), 1.0f);
        pooled[g * 32 + f] = s * inv;
    }
}

__global__ void final_kernel(const float* __restrict__ pooled,
                             const float* __restrict__ Wl, const float* __restrict__ bl,
                             float* __restrict__ out) {
    int idx = blockIdx.x * blockDim.x + threadIdx.x;  // [0, 64*768)
    int g = idx / OUTD, o = idx - g * OUTD;
    float acc = bl[o];
#pragma unroll
    for (int k = 0; k < 32; ++k)
        acc = fmaf(pooled[g * 32 + k], Wl[k * OUTD + o], acc);
    out[idx] = acc;
}

// ---------------------------------------------------------------------------
extern "C" void kernel_launch(void* const* d_in, const int* in_sizes, int n_in,
                              void* d_out, int out_size, void* d_ws, size_t ws_size,
                              hipStream_t stream) {
    const float* x = (const float*)d_in[0];
    const int* eidx = (const int*)d_in[1];
    const float* ea = (const float*)d_in[2];
    const int* batch = (const int*)d_in[3];
    const float* W1 = (const float*)d_in[4];
    const float* b1 = (const float*)d_in[5];
    const float* W2 = (const float*)d_in[6];
    const float* b2 = (const float*)d_in[7];
    const float* W3 = (const float*)d_in[8];
    const float* b3 = (const float*)d_in[9];
    const float* Wl = (const float*)d_in[10];
    const float* bl = (const float*)d_in[11];
    const int* src = eidx;
    const int* dst = eidx + NE;

    char* p = (char*)d_ws;
    auto take = [&](size_t bytes) {
        char* r = p;
        p += (bytes + 255) & ~(size_t)255;
        return r;
    };
    float* dinv = (float*)take(NN * 4);
    float* invdeg = (float*)take(NN * 4);
    int* hist = (int*)take(NN * 4);
    int* rowptr = (int*)take((NN + 1) * 4);
    int* blocksum = (int*)take(256 * 4);
    int* blockoff = (int*)take(256 * 4);
    int2* epack = (int2*)take((size_t)NE * 8);
    float* pooled = (float*)take(NG * 32 * 4);
    unsigned int* wmax = (unsigned int*)take(4);
    unsigned short* bufA = (unsigned short*)take((size_t)NN * 128 * 2);
    unsigned short* bufB = (unsigned short*)take((size_t)NN * 128 * 2);
    // rank & pcnt alias bufB (12.8 MB): both fully consumed by scat_kernel,
    // which completes before agg1 writes bufB (stream-ordered).
    int* rank = (int*)bufB;                                        // 3.2 MB
    unsigned short* pcnt = (unsigned short*)((char*)bufB + (size_t)NE * 4 + 256);  // 6.4 MB

    const int nblk = (NN + 255) / 256;   // 196
    const int eblk = (NE + 255) / 256;   // 3125

    hipMemsetAsync(wmax, 0, 4, stream);

    constexpr int LDS1 = gemm_lds_bytes<64, 64>();   // 33024 -> 4 blocks/CU
    static_assert(LDS1 >= NTL * 4, "HR branch LDS must fit");
    // gemm1 || max || hist-rank — mutually independent, co-scheduled
    fused1_kernel<<<G1B + MAXB + HRB, 256, LDS1, stream>>>(x, W1, bufA, ea, wmax,
                                                           dst, rank, pcnt);
    comb_kernel<<<nblk, 256, 0, stream>>>(pcnt, hist, blocksum);
    scan2_kernel<<<1, 256, 0, stream>>>(blocksum, blockoff, &rowptr[NN], nblk);
    scan3_kernel<<<nblk, 256, 0, stream>>>(hist, blockoff, rowptr, NN);
    scat_kernel<<<eblk, 256, 0, stream>>>(src, dst, ea, rowptr, pcnt, rank, epack, NE);
    deg_kernel<<<nblk, 256, 0, stream>>>(epack, rowptr, wmax, dinv, invdeg, NN);
    coef_kernel<<<nblk, 256, 0, stream>>>(epack, rowptr, dinv, wmax, NN);

    // layer 1 aggregate (gemm1 already done inside fused1)
    agg_kernel<128><<<(NN + 3) / 4, 256, 0, stream>>>(bufA, rowptr, epack, invdeg, b1, bufB, NN);
    // layer 2: 128->64
    gemm_kernel<128, 64, 64, 64>
        <<<dim3((NN + 63) / 64, 1), 256, gemm_lds_bytes<64, 64>(), stream>>>(bufB, W2, bufA, NN);
    agg_kernel<64><<<(NN + 3) / 4, 256, 0, stream>>>(bufA, rowptr, epack, invdeg, b2, bufB, NN);
    // layer 3: 64->32
    gemm_kernel<64, 32, 32, 32>
        <<<dim3((NN + 127) / 128, 1), 256, gemm_lds_bytes<32, 32>(), stream>>>(bufB, W3, bufA, NN);
    agg_kernel<32><<<(NN + 7) / 8 * 2, 256, 0, stream>>>(bufA, rowptr, epack, invdeg, b3, bufB, NN);

    pool2_kernel<<<NG, 256, 0, stream>>>(bufB, batch, pooled, NN);
    final_kernel<<<(NG * OUTD) / 256, 256, 0, stream>>>(pooled, Wl, bl, (float*)d_out);
}

// Round 9
// 294.041 us; speedup vs baseline: 3.9496x; 1.1035x over previous
//
#include <hip/hip_runtime.h>
#include <hip/hip_bf16.h>

// Problem constants (fixed by the reference)
#define NN 50000
#define NE 800000
#define NG 64
#define OUTD 768

// fused1 block-range dispatch: [gemm1(mfma) | max | hist-rank]
#define G1B ((NN + 63) / 64)        // 782 gemm1 blocks (64 rows/block)
#define MAXB 128                    // max-reduce blocks
#define SSEG 64                     // edge segments
#define TTL 8                       // node tiles (25 KB LDS counters)
#define ESEG (NE / SSEG)            // 12500 edges / segment
#define NTL (NN / TTL)              // 6250 nodes / tile
#define HRB (SSEG * TTL)            // 512 hist-rank blocks

// bf16 helpers: storage is ushort, math is fp32 (RTN-even on store)
__device__ __forceinline__ float bflo(unsigned int u) { return __uint_as_float(u << 16); }
__device__ __forceinline__ float bfhi(unsigned int u) { return __uint_as_float(u & 0xffff0000u); }
__device__ __forceinline__ unsigned short f2bf(float f) {
    unsigned int u = __float_as_uint(f);
    return (unsigned short)((u + 0x7fffu + ((u >> 16) & 1u)) >> 16);
}
__device__ __forceinline__ unsigned int pack2bf(float lo, float hi) {
    return (unsigned int)f2bf(lo) | ((unsigned int)f2bf(hi) << 16);
}

typedef __attribute__((ext_vector_type(8))) short bf16x8;
typedef __attribute__((ext_vector_type(4))) float f32x4;
union FragU { uint4 u4; bf16x8 v; };

// ---------------------------------------------------------------------------
// MFMA GEMM: Y[N rows][Ncols](bf16) = X[rows][K] @ W[K][Ncols], fp32 acc.
// W staged to LDS as bf16 B-fragments (lane n=lane&15, k=quad*8+j).
// A loaded from global per wave (16 rows), fp32 X converted in-register.
// C/D layout: col=lane&15, row=quad*4+reg  [m89-verified].
template <int K, int N>
constexpr int mfma_lds_bytes() { return (K / 32) * (N / 16) * 1024; }

template <int K, int N, typename TX>
__device__ __forceinline__ void mfma_gemm_body(char* smem,
                                               const TX* __restrict__ X,
                                               const float* __restrict__ W,
                                               unsigned short* __restrict__ Y,
                                               int nRows, int bx) {
    constexpr int NCT = N / 16;   // col tiles
    constexpr int KS = K / 32;    // k steps
    const int tid = threadIdx.x;

    // stage W -> LDS bf16 fragments: frag fi=(kc*NCT+ct), entry lane*16B
    for (int q = tid; q < KS * NCT * 64; q += 256) {
        int lane = q & 63;
        int fi = q >> 6;
        int ct = fi % NCT, kc = fi / NCT;
        int col = ct * 16 + (lane & 15);
        int kb = kc * 32 + ((lane >> 4) << 3);
        uint4 w;
        w.x = pack2bf(W[(size_t)(kb + 0) * N + col], W[(size_t)(kb + 1) * N + col]);
        w.y = pack2bf(W[(size_t)(kb + 2) * N + col], W[(size_t)(kb + 3) * N + col]);
        w.z = pack2bf(W[(size_t)(kb + 4) * N + col], W[(size_t)(kb + 5) * N + col]);
        w.w = pack2bf(W[(size_t)(kb + 6) * N + col], W[(size_t)(kb + 7) * N + col]);
        *(uint4*)(smem + (size_t)q * 16) = w;
    }
    __syncthreads();

    const int lane = tid & 63;
    const int wv = tid >> 6;          // wave 0..3 -> 16 rows each
    const int m = lane & 15;
    const int quad = lane >> 4;
    const int row = bx * 64 + wv * 16 + m;
    const bool rowok = row < nRows;
    const TX* xr = X + (size_t)(rowok ? row : 0) * K;

    f32x4 acc[NCT];
#pragma unroll
    for (int ct = 0; ct < NCT; ++ct) acc[ct] = (f32x4){0.f, 0.f, 0.f, 0.f};

#pragma unroll
    for (int kc = 0; kc < KS; ++kc) {
        const int k0 = kc * 32 + quad * 8;
        FragU a;
        if constexpr (sizeof(TX) == 4) {   // fp32 X -> cvt to bf16
            float4 a0 = make_float4(0.f, 0.f, 0.f, 0.f), a1 = a0;
            if (rowok) {
                a0 = *(const float4*)(xr + k0);
                a1 = *(const float4*)(xr + k0 + 4);
            }
            a.u4 = make_uint4(pack2bf(a0.x, a0.y), pack2bf(a0.z, a0.w),
                              pack2bf(a1.x, a1.y), pack2bf(a1.z, a1.w));
        } else {                           // bf16 X direct
            a.u4 = rowok ? *(const uint4*)(xr + k0) : make_uint4(0, 0, 0, 0);
        }
#pragma unroll
        for (int ct = 0; ct < NCT; ++ct) {
            FragU b;
            b.u4 = *(const uint4*)(smem + ((size_t)(kc * NCT + ct) * 64 + lane) * 16);
            acc[ct] = __builtin_amdgcn_mfma_f32_16x16x32_bf16(a.v, b.v, acc[ct], 0, 0, 0);
        }
    }

    const int orowb = bx * 64 + wv * 16 + quad * 4;
#pragma unroll
    for (int ct = 0; ct < NCT; ++ct) {
        int col = ct * 16 + m;
#pragma unroll
        for (int r = 0; r < 4; ++r) {
            int orow = orowb + r;
            if (orow < nRows) Y[(size_t)orow * N + col] = f2bf(acc[ct][r]);
        }
    }
}

template <int K, int N, typename TX>
__global__ __launch_bounds__(256) void mfma_gemm_kernel(const TX* __restrict__ X,
                                                        const float* __restrict__ W,
                                                        unsigned short* __restrict__ Y,
                                                        int nRows) {
    extern __shared__ char smem[];
    mfma_gemm_body<K, N>(smem, X, W, Y, nRows, blockIdx.x);
}

// ---------------------------------------------------------------------------
// fused1: [0,G1B) gemm1 MFMA (x fp32 @ W1 -> bf16); [G1B,G1B+MAXB) max(ea);
// rest: hist-rank counting via LDS (NO global atomics).
__global__ __launch_bounds__(256) void fused1_kernel(const float* __restrict__ x,
                                                     const float* __restrict__ W1,
                                                     unsigned short* __restrict__ bufA,
                                                     const float* __restrict__ ea,
                                                     unsigned int* wmax,
                                                     const int* __restrict__ dst,
                                                     int* __restrict__ rank,
                                                     unsigned short* __restrict__ pcnt) {
    extern __shared__ char smem[];
    const int b = blockIdx.x;
    if (b < G1B) {
        mfma_gemm_body<128, 128>(smem, x, W1, bufA, NN, b);
    } else if (b < G1B + MAXB) {
        float* red = (float*)smem;
        const int bb = b - G1B;
        float m = 0.0f;
        for (int i = bb * 256 + threadIdx.x; i < NE; i += MAXB * 256)
            m = fmaxf(m, ea[i]);
        red[threadIdx.x] = m;
        __syncthreads();
        for (int off = 128; off > 0; off >>= 1) {
            if (threadIdx.x < off)
                red[threadIdx.x] = fmaxf(red[threadIdx.x], red[threadIdx.x + off]);
            __syncthreads();
        }
        if (threadIdx.x == 0) atomicMax(wmax, __float_as_uint(red[0]));
    } else {
        const int b2 = b - G1B - MAXB;   // 0..HRB-1
        const int seg = b2 >> 3;         // TTL == 8
        const int tile = b2 & 7;
        int* lcnt = (int*)smem;          // NTL ints = 25 KB (< 32 KB alloc)
        for (int i = threadIdx.x; i < NTL; i += 256) lcnt[i] = 0;
        __syncthreads();
        const int base = seg * ESEG;
        const int nlo = tile * NTL;
        for (int e = base + threadIdx.x; e < base + ESEG; e += 256) {
            int d = dst[e] - nlo;
            if ((unsigned)d < (unsigned)NTL)
                rank[e] = atomicAdd(&lcnt[d], 1);   // LDS atomic
        }
        __syncthreads();
        unsigned short* prow = pcnt + (size_t)seg * NN + nlo;
        for (int i = threadIdx.x; i < NTL; i += 256)
            prow[i] = (unsigned short)lcnt[i];
    }
}

// Per-node: exclusive prefix over segments (in place, u16), total -> hist,
// and fused block-reduction of totals -> blocksum.
__global__ __launch_bounds__(256) void comb_kernel(unsigned short* __restrict__ pcnt,
                                                   int* __restrict__ hist,
                                                   int* __restrict__ blocksum) {
    __shared__ int red[256];
    int n = blockIdx.x * 256 + threadIdx.x;
    int run = 0;
    if (n < NN) {
#pragma unroll
        for (int s = 0; s < SSEG; ++s) {
            size_t idx = (size_t)s * NN + n;
            int v = pcnt[idx];
            pcnt[idx] = (unsigned short)run;
            run += v;
        }
        hist[n] = run;
    }
    red[threadIdx.x] = (n < NN) ? run : 0;
    __syncthreads();
    for (int off = 128; off > 0; off >>= 1) {
        if (threadIdx.x < off) red[threadIdx.x] += red[threadIdx.x + off];
        __syncthreads();
    }
    if (threadIdx.x == 0) blocksum[blockIdx.x] = red[0];
}

__global__ __launch_bounds__(256) void scan2_kernel(const int* __restrict__ blocksum,
                                                    int* __restrict__ blockoff,
                                                    int* __restrict__ total_out, int nb) {
    __shared__ int s[256];
    const int tid = threadIdx.x;
    int v = (tid < nb) ? blocksum[tid] : 0;
    s[tid] = v;
    __syncthreads();
    for (int off = 1; off < 256; off <<= 1) {
        int t = (tid >= off) ? s[tid - off] : 0;
        __syncthreads();
        s[tid] += t;
        __syncthreads();
    }
    if (tid < nb) blockoff[tid] = s[tid] - v;
    if (tid == nb - 1) *total_out = s[tid];
}

__global__ __launch_bounds__(256) void scan3_kernel(const int* __restrict__ hist,
                                                    const int* __restrict__ blockoff,
                                                    int* __restrict__ rowptr, int n) {
    __shared__ int s[256];
    const int tid = threadIdx.x;
    int i = blockIdx.x * 256 + tid;
    int v = (i < n) ? hist[i] : 0;
    s[tid] = v;
    __syncthreads();
    for (int off = 1; off < 256; off <<= 1) {
        int t = (tid >= off) ? s[tid - off] : 0;
        __syncthreads();
        s[tid] += t;
        __syncthreads();
    }
    if (i < n) rowptr[i] = blockoff[blockIdx.x] + s[tid] - v;
}

// ---------------------------------------------------------------------------
// Atomic-free scatter: pos = rowptr[d] + pcnt[seg][d] + rank[e].
__global__ void scat_kernel(const int* __restrict__ src, const int* __restrict__ dst,
                            const float* __restrict__ ea,
                            const int* __restrict__ rowptr,
                            const unsigned short* __restrict__ pcnt,
                            const int* __restrict__ rank,
                            int2* __restrict__ epack, int nE) {
    int e = blockIdx.x * blockDim.x + threadIdx.x;
    if (e >= nE) return;
    int s = e / ESEG;
    int d = dst[e];
    int pos = rowptr[d] + (int)pcnt[(size_t)s * NN + d] + rank[e];
    epack[pos] = make_int2(src[e], __float_as_int(ea[e]));
}

// deg from contiguous CSR segments (no atomics): deg = 1 + rw * sum(ea)
__global__ void deg_kernel(const int2* __restrict__ epack, const int* __restrict__ rowptr,
                           const unsigned int* __restrict__ wmax,
                           float* __restrict__ dinv, float* __restrict__ invdeg, int n) {
    int i = blockIdx.x * blockDim.x + threadIdx.x;
    if (i >= n) return;
    float rw = 1.0f / __uint_as_float(*wmax);
    int s0 = rowptr[i], s1 = rowptr[i + 1];
    float s = 0.f;
    for (int e = s0; e < s1; ++e) s += __int_as_float(epack[e].y);
    float d = fmaf(s, rw, 1.0f);
    dinv[i] = rsqrtf(d);
    invdeg[i] = 1.0f / d;
}

// rewrite epack.y: raw ea -> layer-invariant coefficient
__global__ void coef_kernel(int2* __restrict__ epack, const int* __restrict__ rowptr,
                            const float* __restrict__ dinv,
                            const unsigned int* __restrict__ wmax, int n) {
    int i = blockIdx.x * blockDim.x + threadIdx.x;
    if (i >= n) return;
    float rw = 1.0f / __uint_as_float(*wmax);
    float di = dinv[i];
    int s0 = rowptr[i], s1 = rowptr[i + 1];
    for (int e = s0; e < s1; ++e) {
        int2 p = epack[e];
        p.y = __float_as_int(dinv[p.x] * (__int_as_float(p.y) * rw) * di);
        epack[e] = p;
    }
}

// ---------------------------------------------------------------------------
// Aggregation over bf16 H: out = relu( sum coef*H[src] + invdeg[n]*H[n] + b ).
// One node per wave; EPW = 64/(D/8) edges in flight per iter, 16B (8 bf16)
// per lane, fp32 accumulate, shfl_xor combine, bf16 store.
template <int D>
__global__ __launch_bounds__(256) void agg_kernel(const unsigned short* __restrict__ H,
                                                  const int* __restrict__ rowptr,
                                                  const int2* __restrict__ epack,
                                                  const float* __restrict__ invdeg,
                                                  const float* __restrict__ bias,
                                                  unsigned short* __restrict__ out,
                                                  int nNodes) {
    constexpr int LPE = D / 8;    // lanes per edge (16 / 8 / 4)
    constexpr int EPW = 64 / LPE; // edges per iter  (4 / 8 / 16)
    const int lane = threadIdx.x & 63;
    const int n = (blockIdx.x << 2) | (threadIdx.x >> 6);
    if (n >= nNodes) return;
    const int esub = lane / LPE;
    const int f8 = (lane % LPE) * 8;
    const int s0 = rowptr[n];
    const int cnt = rowptr[n + 1] - s0;

    float a[8] = {};
    int kb = 0;
    for (; kb + 2 * EPW <= cnt; kb += 2 * EPW) {
        const int2 pa = epack[s0 + kb + esub];
        const int2 pb = epack[s0 + kb + EPW + esub];
        const uint4 ua = *(const uint4*)(H + (size_t)pa.x * D + f8);
        const uint4 ub = *(const uint4*)(H + (size_t)pb.x * D + f8);
        const float ca = __int_as_float(pa.y);
        const float cb = __int_as_float(pb.y);
        a[0] = fmaf(ca, bflo(ua.x), a[0]); a[1] = fmaf(ca, bfhi(ua.x), a[1]);
        a[2] = fmaf(ca, bflo(ua.y), a[2]); a[3] = fmaf(ca, bfhi(ua.y), a[3]);
        a[4] = fmaf(ca, bflo(ua.z), a[4]); a[5] = fmaf(ca, bfhi(ua.z), a[5]);
        a[6] = fmaf(ca, bflo(ua.w), a[6]); a[7] = fmaf(ca, bfhi(ua.w), a[7]);
        a[0] = fmaf(cb, bflo(ub.x), a[0]); a[1] = fmaf(cb, bfhi(ub.x), a[1]);
        a[2] = fmaf(cb, bflo(ub.y), a[2]); a[3] = fmaf(cb, bfhi(ub.y), a[3]);
        a[4] = fmaf(cb, bflo(ub.z), a[4]); a[5] = fmaf(cb, bfhi(ub.z), a[5]);
        a[6] = fmaf(cb, bflo(ub.w), a[6]); a[7] = fmaf(cb, bfhi(ub.w), a[7]);
    }
    for (; kb < cnt; kb += EPW) {   // <= 2 guarded tail iterations
        const int idx = kb + esub;
        const bool ok = idx < cnt;
        const int2 p = ok ? epack[s0 + idx] : make_int2(n, 0);
        const uint4 u = *(const uint4*)(H + (size_t)p.x * D + f8);
        const float c = ok ? __int_as_float(p.y) : 0.f;
        a[0] = fmaf(c, bflo(u.x), a[0]); a[1] = fmaf(c, bfhi(u.x), a[1]);
        a[2] = fmaf(c, bflo(u.y), a[2]); a[3] = fmaf(c, bfhi(u.y), a[3]);
        a[4] = fmaf(c, bflo(u.z), a[4]); a[5] = fmaf(c, bfhi(u.z), a[5]);
        a[6] = fmaf(c, bflo(u.w), a[6]); a[7] = fmaf(c, bfhi(u.w), a[7]);
    }
#pragma unroll
    for (int off = LPE; off < 64; off <<= 1) {
#pragma unroll
        for (int j = 0; j < 8; ++j) a[j] += __shfl_xor(a[j], off);
    }
    if (esub == 0) {
        const float id = invdeg[n];
        const uint4 un = *(const uint4*)(H + (size_t)n * D + f8);
        const float4 b0 = *(const float4*)(bias + f8);
        const float4 b1 = *(const float4*)(bias + f8 + 4);
        float o[8];
        o[0] = fmaxf(fmaf(id, bflo(un.x), a[0]) + b0.x, 0.f);
        o[1] = fmaxf(fmaf(id, bfhi(un.x), a[1]) + b0.y, 0.f);
        o[2] = fmaxf(fmaf(id, bflo(un.y), a[2]) + b0.z, 0.f);
        o[3] = fmaxf(fmaf(id, bfhi(un.y), a[3]) + b0.w, 0.f);
        o[4] = fmaxf(fmaf(id, bflo(un.z), a[4]) + b1.x, 0.f);
        o[5] = fmaxf(fmaf(id, bfhi(un.z), a[5]) + b1.y, 0.f);
        o[6] = fmaxf(fmaf(id, bflo(un.w), a[6]) + b1.z, 0.f);
        o[7] = fmaxf(fmaf(id, bfhi(un.w), a[7]) + b1.w, 0.f);
        uint4 w;
        w.x = pack2bf(o[0], o[1]);
        w.y = pack2bf(o[2], o[3]);
        w.z = pack2bf(o[4], o[5]);
        w.w = pack2bf(o[6], o[7]);
        *(uint4*)(out + (size_t)n * D + f8) = w;
    }
}

// ---------------------------------------------------------------------------
// Pool (bf16 input): batch SORTED -> one block per graph, binary search range.
__global__ __launch_bounds__(256) void pool2_kernel(const unsigned short* __restrict__ h,
                                                    const int* __restrict__ batch,
                                                    float* __restrict__ pooled, int n) {
    const int g = blockIdx.x;
    int lo = 0, hi = n;
    while (lo < hi) { int m = (lo + hi) >> 1; if (batch[m] < g) lo = m + 1; else hi = m; }
    const int start = lo;
    lo = start; hi = n;
    while (lo < hi) { int m = (lo + hi) >> 1; if (batch[m] < g + 1) lo = m + 1; else hi = m; }
    const int end = lo;

    __shared__ float part[256];
    const int f = threadIdx.x & 31;
    const int r = threadIdx.x >> 5;  // 0..7
    float acc = 0.f;
    for (int i = start + r; i < end; i += 8)
        acc += __uint_as_float((unsigned int)h[(size_t)i * 32 + f] << 16);
    part[threadIdx.x] = acc;
    __syncthreads();
    if (threadIdx.x < 32) {
        float s = 0.f;
#pragma unroll
        for (int q = 0; q < 8; ++q) s += part[q * 32 + f];
        float inv = 1.0f / fmaxf((float)(end - start), 1.0f);
        pooled[g * 32 + f] = s * inv;
    }
}

__global__ void final_kernel(const float* __restrict__ pooled,
                             const float* __restrict__ Wl, const float* __restrict__ bl,
                             float* __restrict__ out) {
    int idx = blockIdx.x * blockDim.x + threadIdx.x;  // [0, 64*768)
    int g = idx / OUTD, o = idx - g * OUTD;
    float acc = bl[o];
#pragma unroll
    for (int k = 0; k < 32; ++k)
        acc = fmaf(pooled[g * 32 + k], Wl[k * OUTD + o], acc);
    out[idx] = acc;
}

// ---------------------------------------------------------------------------
extern "C" void kernel_launch(void* const* d_in, const int* in_sizes, int n_in,
                              void* d_out, int out_size, void* d_ws, size_t ws_size,
                              hipStream_t stream) {
    const float* x = (const float*)d_in[0];
    const int* eidx = (const int*)d_in[1];
    const float* ea = (const float*)d_in[2];
    const int* batch = (const int*)d_in[3];
    const float* W1 = (const float*)d_in[4];
    const float* b1 = (const float*)d_in[5];
    const float* W2 = (const float*)d_in[6];
    const float* b2 = (const float*)d_in[7];
    const float* W3 = (const float*)d_in[8];
    const float* b3 = (const float*)d_in[9];
    const float* Wl = (const float*)d_in[10];
    const float* bl = (const float*)d_in[11];
    const int* src = eidx;
    const int* dst = eidx + NE;

    char* p = (char*)d_ws;
    auto take = [&](size_t bytes) {
        char* r = p;
        p += (bytes + 255) & ~(size_t)255;
        return r;
    };
    float* dinv = (float*)take(NN * 4);
    float* invdeg = (float*)take(NN * 4);
    int* hist = (int*)take(NN * 4);
    int* rowptr = (int*)take((NN + 1) * 4);
    int* blocksum = (int*)take(256 * 4);
    int* blockoff = (int*)take(256 * 4);
    int2* epack = (int2*)take((size_t)NE * 8);
    float* pooled = (float*)take(NG * 32 * 4);
    unsigned int* wmax = (unsigned int*)take(4);
    unsigned short* bufA = (unsigned short*)take((size_t)NN * 128 * 2);
    unsigned short* bufB = (unsigned short*)take((size_t)NN * 128 * 2);
    // rank & pcnt alias bufB (12.8 MB): both fully consumed by scat_kernel,
    // which completes before agg1 writes bufB (stream-ordered).
    int* rank = (int*)bufB;                                        // 3.2 MB
    unsigned short* pcnt = (unsigned short*)((char*)bufB + (size_t)NE * 4 + 256);  // 6.4 MB

    const int nblk = (NN + 255) / 256;   // 196
    const int eblk = (NE + 255) / 256;   // 3125

    hipMemsetAsync(wmax, 0, 4, stream);

    constexpr int LDS1 = mfma_lds_bytes<128, 128>();   // 32768 (>= 25 KB HR need)
    static_assert(LDS1 >= NTL * 4, "HR branch LDS must fit");
    // gemm1(mfma) || max || hist-rank — mutually independent, co-scheduled
    fused1_kernel<<<G1B + MAXB + HRB, 256, LDS1, stream>>>(x, W1, bufA, ea, wmax,
                                                           dst, rank, pcnt);
    comb_kernel<<<nblk, 256, 0, stream>>>(pcnt, hist, blocksum);
    scan2_kernel<<<1, 256, 0, stream>>>(blocksum, blockoff, &rowptr[NN], nblk);
    scan3_kernel<<<nblk, 256, 0, stream>>>(hist, blockoff, rowptr, NN);
    scat_kernel<<<eblk, 256, 0, stream>>>(src, dst, ea, rowptr, pcnt, rank, epack, NE);
    deg_kernel<<<nblk, 256, 0, stream>>>(epack, rowptr, wmax, dinv, invdeg, NN);
    coef_kernel<<<nblk, 256, 0, stream>>>(epack, rowptr, dinv, wmax, NN);

    // layer 1 aggregate (gemm1 already done inside fused1)
    agg_kernel<128><<<(NN + 3) / 4, 256, 0, stream>>>(bufA, rowptr, epack, invdeg, b1, bufB, NN);
    // layer 2: 128->64 (MFMA)
    mfma_gemm_kernel<128, 64, unsigned short>
        <<<G1B, 256, mfma_lds_bytes<128, 64>(), stream>>>(bufB, W2, bufA, NN);
    agg_kernel<64><<<(NN + 3) / 4, 256, 0, stream>>>(bufA, rowptr, epack, invdeg, b2, bufB, NN);
    // layer 3: 64->32 (MFMA)
    mfma_gemm_kernel<64, 32, unsigned short>
        <<<G1B, 256, mfma_lds_bytes<64, 32>(), stream>>>(bufB, W3, bufA, NN);
    agg_kernel<32><<<(NN + 7) / 8 * 2, 256, 0, stream>>>(bufA, rowptr, epack, invdeg, b3, bufB, NN);

    pool2_kernel<<<NG, 256, 0, stream>>>(bufB, batch, pooled, NN);
    final_kernel<<<(NG * OUTD) / 256, 256, 0, stream>>>(pooled, Wl, bl, (float*)d_out);
}